// Round 3
// baseline (397.500 us; speedup 1.0000x reference)
//
#include <hip/hip_runtime.h>
#include <math.h>

#define HID 128
#define HEADS 4
#define NEG_SLOPE 0.2f
#define R1B 1024   // reduce1 grid
#define BCAP 8192  // per-bucket arena capacity (mean 4096, +64 sigma)
#define PB 6144    // binB LDS staging ints
#define ACHUNK 4096

typedef float f32x4 __attribute__((ext_vector_type(4)));
typedef _Float16 f16x8 __attribute__((ext_vector_type(8)));
typedef _Float16 f16x4 __attribute__((ext_vector_type(4)));
typedef _Float16 f16x2 __attribute__((ext_vector_type(2)));

#if defined(__has_builtin)
#if __has_builtin(__builtin_amdgcn_fdot2)
#define HAVE_FDOT2 1
#endif
#endif

// ---------------- CSR build: two-phase binned counting sort ----------------

__global__ __launch_bounds__(256) void k_zero_int(int* p, int n) {
    int i = blockIdx.x * blockDim.x + threadIdx.x;
    if (i < n) p[i] = 0;
}

// Phase A: bin 4096 edges/block into bucket arenas. Record = (src<<8)|(dst&255).
__global__ __launch_bounds__(256) void k_binA(const int* __restrict__ src, const int* __restrict__ dst,
                                              int E, int* __restrict__ gcnt, int* __restrict__ arena) {
    __shared__ int lh[256];
    __shared__ int lbase[256];
    __shared__ unsigned short lrank[ACHUNK];
    const int tid = threadIdx.x;
    lh[tid] = 0;
    __syncthreads();
    const int e0 = blockIdx.x * ACHUNK;
    #pragma unroll
    for (int i = 0; i < ACHUNK / 256; i++) {
        int e = e0 + i * 256 + tid;
        if (e < E) {
            int b = dst[e] >> 8;
            lrank[i * 256 + tid] = (unsigned short)atomicAdd(&lh[b], 1);
        }
    }
    __syncthreads();
    if (lh[tid] > 0) lbase[tid] = atomicAdd(&gcnt[tid], lh[tid]);
    __syncthreads();
    #pragma unroll
    for (int i = 0; i < ACHUNK / 256; i++) {
        int e = e0 + i * 256 + tid;
        if (e < E) {
            int d = dst[e];
            int b = d >> 8;
            arena[b * BCAP + lbase[b] + lrank[i * 256 + tid]] = (src[e] << 8) | (d & 255);
        }
    }
}

// exclusive scan of bucket counts -> bucket segment starts; rowptr[N]=E
__global__ __launch_bounds__(256) void k_scan_bk(const int* __restrict__ gcnt, int nbk,
                                                 int* __restrict__ bstart, int* __restrict__ rowptr,
                                                 int N, int E) {
    __shared__ int buf[256];
    int tid = threadIdx.x;
    int v = (tid < nbk) ? gcnt[tid] : 0;
    buf[tid] = v;
    __syncthreads();
    for (int off = 1; off < 256; off <<= 1) {
        int t = (tid >= off) ? buf[tid - off] : 0;
        __syncthreads();
        buf[tid] += t;
        __syncthreads();
    }
    bstart[tid] = buf[tid] - v;
    if (tid == 0) rowptr[N] = E;
}

// Phase B: per bucket -- node counts + scan in LDS -> rowptr; staged,
// coalesced csr_off dump. csr_off value = src*256 = record & ~255.
__global__ __launch_bounds__(256) void k_binB(const int* __restrict__ arena, const int* __restrict__ gcnt,
                                              const int* __restrict__ bstart, int N,
                                              int* __restrict__ rowptr, int* __restrict__ csr_off) {
    __shared__ int ncnt[256];
    __shared__ int sbuf[256];
    __shared__ int nstart[256];
    __shared__ int stage[PB];
    __shared__ unsigned short rk[BCAP];
    const int b = blockIdx.x, tid = threadIdx.x;
    const int cnt = gcnt[b];
    const int seg = bstart[b];
    ncnt[tid] = 0;
    __syncthreads();
    for (int k = tid; k < cnt; k += 256) {
        int v = arena[b * BCAP + k];
        rk[k] = (unsigned short)atomicAdd(&ncnt[v & 255], 1);
    }
    __syncthreads();
    int c = ncnt[tid];
    sbuf[tid] = c;
    __syncthreads();
    for (int off = 1; off < 256; off <<= 1) {
        int t = (tid >= off) ? sbuf[tid - off] : 0;
        __syncthreads();
        sbuf[tid] += t;
        __syncthreads();
    }
    int myStart = sbuf[tid] - c;   // exclusive
    nstart[tid] = myStart;
    int n = b * 256 + tid;
    if (n < N) rowptr[n] = seg + myStart;
    __syncthreads();
    for (int k = tid; k < cnt; k += 256) {
        int v = arena[b * BCAP + k];
        int pos = nstart[v & 255] + rk[k];
        int val = v & 0xFFFFFF00;
        if (pos < PB) stage[pos] = val;
        else          csr_off[seg + pos] = val;   // statistical overflow guard
    }
    __syncthreads();
    int lim = min(cnt, PB);
    for (int k = tid; k < lim; k += 256) csr_off[seg + k] = stage[k];
}

// ---------------- helpers ----------------

__device__ inline f16x2 absh2(f16x2 v) {
    unsigned u = __builtin_bit_cast(unsigned, v) & 0x7FFF7FFFu;
    return __builtin_bit_cast(f16x2, u);
}

// quad_perm butterfly add via DPP: replaces ds_swizzle-based __shfl_xor(p,1/2).
// Head groups (4 lanes) are hardware quads: xor1 = quad_perm 0xB1, xor2 = 0x4E.
// ctrl must be a compile-time constant -> template parameter.
template <int CTRL>
__device__ inline float qp_xor_add(float x) {
    int y = __builtin_amdgcn_update_dpp(0, __builtin_bit_cast(int, x),
                                        CTRL, 0xF, 0xF, true);
    return x + __builtin_bit_cast(float, y);
}

// per-edge logit: leaky_relu(xl+xr) . att  (packed fp16, fdot2 accumulate)
__device__ inline float edge_logit(f16x2 c0, f16x2 c1, f16x2 c2, f16x2 c3,
                                   f16x2 xr0, f16x2 xr1, f16x2 xr2, f16x2 xr3,
                                   f16x2 a0, f16x2 a1, f16x2 a2, f16x2 a3) {
    const f16x2 k06 = (f16x2){(_Float16)0.6f, (_Float16)0.6f};
    const f16x2 k04 = (f16x2){(_Float16)0.4f, (_Float16)0.4f};
    f16x2 u0 = c0 + xr0, u1 = c1 + xr1, u2 = c2 + xr2, u3 = c3 + xr3;
    f16x2 l0 = u0 * k06 + absh2(u0) * k04;   // leaky_relu, packed
    f16x2 l1 = u1 * k06 + absh2(u1) * k04;
    f16x2 l2 = u2 * k06 + absh2(u2) * k04;
    f16x2 l3 = u3 * k06 + absh2(u3) * k04;
#ifdef HAVE_FDOT2
    float p = __builtin_amdgcn_fdot2(l0, a0, 0.f, false);
    p = __builtin_amdgcn_fdot2(l1, a1, p, false);
    p = __builtin_amdgcn_fdot2(l2, a2, p, false);
    p = __builtin_amdgcn_fdot2(l3, a3, p, false);
#else
    float p = (float)l0[0] * (float)a0[0] + (float)l0[1] * (float)a0[1]
            + (float)l1[0] * (float)a1[0] + (float)l1[1] * (float)a1[1]
            + (float)l2[0] * (float)a2[0] + (float)l2[1] * (float)a2[1]
            + (float)l3[0] * (float)a3[0] + (float)l3[1] * (float)a3[1];
#endif
    return p;
}

// fp32 -> fp16 convert for both W matrices in one launch (blockIdx.y selects)
__global__ __launch_bounds__(256) void k_tof16(const float* __restrict__ a, const float* __restrict__ b,
                                               _Float16* __restrict__ oa, _Float16* __restrict__ ob, int n) {
    const float* x = blockIdx.y ? b : a;
    _Float16*    o = blockIdx.y ? ob : oa;
    int base = (blockIdx.x * 256 + threadIdx.x) * 4;
    if (base >= n) return;
    float4 v = *(const float4*)(x + base);
    f16x4 h = {(_Float16)v.x, (_Float16)v.y, (_Float16)v.z, (_Float16)v.w};
    *(f16x4*)(o + base) = h;
}

// ---------------- MFMA linear, LDS-resident fp16 W, 2 A-tiles/wave ----------------
// fp16 inputs, fp32 MFMA accumulate. blockIdx.y: 0 -> xlh ; 1 -> xrh.
// Wave covers 32 nodes x 128 outputs: each ds_read_b128 B-fragment feeds
// TWO MFMAs (ds throughput was the k-loop bottleneck: 8x12cyc ds vs 8x4.85cyc
// MFMA; now 96 ds vs 78 MFMA per k0 - balanced). Block = 512 thr = 256 nodes.

__global__ __launch_bounds__(512) void k_linear_mfma(
        const _Float16* __restrict__ xh,
        const _Float16* __restrict__ WfL, const _Float16* __restrict__ WfR,
        const float* __restrict__ bl, const float* __restrict__ br,
        _Float16* __restrict__ xlh, _Float16* __restrict__ xrh, int N) {
    __shared__ _Float16 lds[16384];   // 32 KB: W fp16, swizzled
    const int t   = threadIdx.x;
    const int mat = blockIdx.y;
    const _Float16* W = mat ? WfR : WfL;

    for (int g = t; g < 2048; g += 512) {
        int r = g >> 4, cc = g & 15;
        int dsto = r * 128 + ((cc ^ (r & 7)) << 3);      // half units
        *(float4*)&lds[dsto] = *(const float4*)(W + g * 8);
    }
    __syncthreads();

    const int wave = t >> 6;
    const int lane = t & 63;
    const int l16  = lane & 15;
    const int quad = lane >> 4;
    const int n0   = blockIdx.x * 256 + wave * 32;

    int arow0 = n0 + l16;
    int arow1 = n0 + 16 + l16;
    if (arow0 >= N) arow0 = N - 1;     // clamp loads; stores guarded below
    if (arow1 >= N) arow1 = N - 1;

    f32x4 acc[2][8];
    #pragma unroll
    for (int u = 0; u < 2; u++)
        #pragma unroll
        for (int s = 0; s < 8; s++) acc[u][s] = (f32x4){0.f, 0.f, 0.f, 0.f};

    #pragma unroll
    for (int k0 = 0; k0 < HID; k0 += 32) {
        f16x8 a0 = *(const f16x8*)(xh + arow0 * HID + k0 + quad * 8);
        f16x8 a1 = *(const f16x8*)(xh + arow1 * HID + k0 + quad * 8);
        const int cc = (k0 >> 3) + quad;
        #pragma unroll
        for (int s = 0; s < 8; s++) {
            const int row = s * 16 + l16;
            const int off = row * 128 + ((cc ^ (l16 & 7)) << 3);
            f16x8 b = *(const f16x8*)&lds[off];
            acc[0][s] = __builtin_amdgcn_mfma_f32_16x16x32_f16(a0, b, acc[0][s], 0, 0, 0);
            acc[1][s] = __builtin_amdgcn_mfma_f32_16x16x32_f16(a1, b, acc[1][s], 0, 0, 0);
        }
    }

    const float* bias = mat ? br : bl;
    _Float16* dst = mat ? xrh : xlh;
    #pragma unroll
    for (int s = 0; s < 8; s++) {
        int col = s * 16 + l16;
        float bv = bias[col];
        #pragma unroll
        for (int u = 0; u < 2; u++) {
            #pragma unroll
            for (int r = 0; r < 4; r++) {
                int node = n0 + u * 16 + quad * 4 + r;
                if (node < N) dst[(size_t)node * HID + col] = (_Float16)(acc[u][s][r] + bv);
            }
        }
    }
}

// ---------------- Fused attention: wave per node, 4 edge streams x 2 edges ----------------
// Round-3: depth-3 row pipeline (6 row buffers; 24 rows in flight per wave;
// prefetch distance = 2 full iterations ~= 520cy of gather-latency cover, vs
// depth-2's ~260cy which left waves stalled ~40% of residency). VGPR grows past
// 64 -> __launch_bounds__(256,7) (cap 73). Epilogue cross-stream merge done on
// packed f16x2 (10 shuffles vs 18); values are O(100) << fp16 max, safe.

__global__ __launch_bounds__(256, 7) void k_attn(const _Float16* __restrict__ xlh, const _Float16* __restrict__ xrh,
                                              const int* __restrict__ rowptr, const int* __restrict__ csr_off,
                                              const float* __restrict__ att, const float* __restrict__ bias,
                                              const _Float16* __restrict__ xres, _Float16* __restrict__ outx,
                                              float* __restrict__ out,
                                              int add_res, int want_half, int N) {
    const int wave = threadIdx.x >> 6;
    const int lane = threadIdx.x & 63;
    const int strm = lane >> 4;          // edge stream 0..3
    const int l16  = lane & 15;          // channels [8*l16, 8*l16+8); head = l16>>2
    const int n = blockIdx.x * 4 + wave;
    if (n >= N) return;

    const float4 aA = *(const float4*)(att + 8 * l16);
    const float4 aB = *(const float4*)(att + 8 * l16 + 4);
    const f16x2 a0 = (f16x2){(_Float16)aA.x, (_Float16)aA.y};
    const f16x2 a1 = (f16x2){(_Float16)aA.z, (_Float16)aA.w};
    const f16x2 a2 = (f16x2){(_Float16)aB.x, (_Float16)aB.y};
    const f16x2 a3 = (f16x2){(_Float16)aB.z, (_Float16)aB.w};
    const f16x8 xrv = *(const f16x8*)(xrh + (size_t)n * HID + 8 * l16);
    const f16x2 xr0 = __builtin_shufflevector(xrv, xrv, 0, 1);
    const f16x2 xr1 = __builtin_shufflevector(xrv, xrv, 2, 3);
    const f16x2 xr2 = __builtin_shufflevector(xrv, xrv, 4, 5);
    const f16x2 xr3 = __builtin_shufflevector(xrv, xrv, 6, 7);
    const int s0 = rowptr[n], s1 = rowptr[n + 1];

    float den = 0.f;
    f16x2 acc16[4];
    #pragma unroll
    for (int q = 0; q < 4; q++) acc16[q] = (f16x2){(_Float16)0.f, (_Float16)0.f};

    const char* xlb = (const char*)xlh + l16 * 16;  // lane's 16B slice within a row

    int j = s0 + 2 * strm;                // stream covers edges {j, j+1} + 8t
    if (j < s1) {
        const int last = s1 - 1;
        // depth-3 prologue: 6 rows + 2 offsets in flight per stream
        f16x8 pa0 = *(const f16x8*)(xlb + csr_off[j]);
        f16x8 pb0 = *(const f16x8*)(xlb + csr_off[min(j + 1, last)]);
        f16x8 pa1 = *(const f16x8*)(xlb + csr_off[min(j + 8, last)]);
        f16x8 pb1 = *(const f16x8*)(xlb + csr_off[min(j + 9, last)]);
        f16x8 pa2 = *(const f16x8*)(xlb + csr_off[min(j + 16, last)]);
        f16x8 pb2 = *(const f16x8*)(xlb + csr_off[min(j + 17, last)]);
        int oa = csr_off[min(j + 24, last)];
        int ob = csr_off[min(j + 25, last)];
        while (j < s1) {
            f16x8 ca = pa0, cb = pb0;
            pa0 = pa1; pb0 = pb1;
            pa1 = pa2; pb1 = pb2;
            pa2 = *(const f16x8*)(xlb + oa);
            pb2 = *(const f16x8*)(xlb + ob);
            oa = csr_off[min(j + 32, last)];
            ob = csr_off[min(j + 33, last)];

            f16x2 ca0 = __builtin_shufflevector(ca, ca, 0, 1);
            f16x2 ca1 = __builtin_shufflevector(ca, ca, 2, 3);
            f16x2 ca2 = __builtin_shufflevector(ca, ca, 4, 5);
            f16x2 ca3 = __builtin_shufflevector(ca, ca, 6, 7);
            f16x2 cb0 = __builtin_shufflevector(cb, cb, 0, 1);
            f16x2 cb1 = __builtin_shufflevector(cb, cb, 2, 3);
            f16x2 cb2 = __builtin_shufflevector(cb, cb, 4, 5);
            f16x2 cb3 = __builtin_shufflevector(cb, cb, 6, 7);

            float pa = edge_logit(ca0, ca1, ca2, ca3, xr0, xr1, xr2, xr3, a0, a1, a2, a3);
            float pb = edge_logit(cb0, cb1, cb2, cb3, xr0, xr1, xr2, xr3, a0, a1, a2, a3);

            // reduce across the 4 lanes of each head group (hardware quad)
            pa = qp_xor_add<0xB1>(pa);   // xor 1
            pa = qp_xor_add<0x4E>(pa);   // xor 2
            pb = qp_xor_add<0xB1>(pb);
            pb = qp_xor_add<0x4E>(pb);

            float wa = __expf(pa);
            float wb = __expf(pb);
            if (j + 1 >= s1) wb = 0.f;   // odd-degree tail guard
            den += wa + wb;
            _Float16 wah = (_Float16)wa, wbh = (_Float16)wb;
            f16x2 wpa = (f16x2){wah, wah};
            f16x2 wpb = (f16x2){wbh, wbh};
            acc16[0] += wpa * ca0;       // v_pk_fma_f16
            acc16[1] += wpa * ca1;
            acc16[2] += wpa * ca2;
            acc16[3] += wpa * ca3;
            acc16[0] += wpb * cb0;
            acc16[1] += wpb * cb1;
            acc16[2] += wpb * cb2;
            acc16[3] += wpb * cb3;
            j += 8;
        }
    }

    // merge the four streams (lane stride 16/32) on packed f16x2: 10 shuffles
    den += __shfl_xor(den, 16);
    den += __shfl_xor(den, 32);
    #pragma unroll
    for (int q = 0; q < 4; q++) {
        float pk = __builtin_bit_cast(float, acc16[q]);
        acc16[q] += __builtin_bit_cast(f16x2, __shfl_xor(pk, 16));
        pk = __builtin_bit_cast(float, acc16[q]);
        acc16[q] += __builtin_bit_cast(f16x2, __shfl_xor(pk, 32));
    }

    if (strm == 0) {
        float acc[8];
        #pragma unroll
        for (int q = 0; q < 4; q++) {
            acc[2 * q]     = (float)acc16[q][0];
            acc[2 * q + 1] = (float)acc16[q][1];
        }
        float4 bA = *(const float4*)(bias + 8 * l16);
        float4 bB = *(const float4*)(bias + 8 * l16 + 4);
        float b[8] = {bA.x, bA.y, bA.z, bA.w, bB.x, bB.y, bB.z, bB.w};
        float inv = (den > 0.f) ? 1.f / den : 0.f;
        float v[8];
        #pragma unroll
        for (int q = 0; q < 8; q++) v[q] = fmaxf(acc[q] * inv + b[q], 0.f);
        if (add_res) {
            f16x8 r = *(const f16x8*)(xres + (size_t)n * HID + 8 * l16);
            #pragma unroll
            for (int q = 0; q < 8; q++) v[q] += (float)r[q];
        }
        if (want_half) {
            f16x8 h;
            #pragma unroll
            for (int q = 0; q < 8; q++) h[q] = (_Float16)v[q];
            *(f16x8*)(outx + (size_t)n * HID + 8 * l16) = h;
        } else {
            *(float4*)(out + (size_t)n * HID + 8 * l16)     = make_float4(v[0], v[1], v[2], v[3]);
            *(float4*)(out + (size_t)n * HID + 8 * l16 + 4) = make_float4(v[4], v[5], v[6], v[7]);
        }
    }
}

// ---------------- Embedding: x = relu(nf @ W_emb.T + b_emb) -> fp16 ----------------

__global__ __launch_bounds__(128) void k_embed(const float* __restrict__ nf, const float* __restrict__ W,
                                               const float* __restrict__ b,
                                               _Float16* __restrict__ xh, int N) {
    __shared__ float f[11];
    int n = blockIdx.x;
    int h = threadIdx.x;
    if (h < 11) f[h] = nf[(size_t)n * 11 + h];
    __syncthreads();
    float acc = b[h];
    #pragma unroll
    for (int k = 0; k < 11; k++) acc += f[k] * W[h * 11 + k];
    xh[(size_t)n * HID + h] = (_Float16)fmaxf(acc, 0.f);
}

// ---------------- Graph readout: mean + max over nodes ----------------

__global__ __launch_bounds__(256) void k_reduce1(const float* __restrict__ x, int N,
                                                 float* __restrict__ psum, float* __restrict__ pmax) {
    __shared__ float ls[8][HID];
    __shared__ float lm[8][HID];
    const int c4 = (threadIdx.x & 31) << 2;   // channel base
    const int rl = threadIdx.x >> 5;          // row lane 0..7
    const int per = (N + gridDim.x - 1) / gridDim.x;
    const int n0 = blockIdx.x * per, n1 = min(N, n0 + per);
    float4 s = make_float4(0.f, 0.f, 0.f, 0.f);
    float4 m = make_float4(-INFINITY, -INFINITY, -INFINITY, -INFINITY);
    for (int n = n0 + rl; n < n1; n += 8) {
        float4 v = *(const float4*)(x + (size_t)n * HID + c4);
        s.x += v.x; s.y += v.y; s.z += v.z; s.w += v.w;
        m.x = fmaxf(m.x, v.x); m.y = fmaxf(m.y, v.y);
        m.z = fmaxf(m.z, v.z); m.w = fmaxf(m.w, v.w);
    }
    *(float4*)&ls[rl][c4] = s;
    *(float4*)&lm[rl][c4] = m;
    __syncthreads();
    if (rl < 4) {
        float4 a = *(float4*)&ls[rl][c4], bq = *(float4*)&ls[rl + 4][c4];
        a.x += bq.x; a.y += bq.y; a.z += bq.z; a.w += bq.w;
        *(float4*)&ls[rl][c4] = a;
        float4 am = *(float4*)&lm[rl][c4], bm = *(float4*)&lm[rl + 4][c4];
        am.x = fmaxf(am.x, bm.x); am.y = fmaxf(am.y, bm.y);
        am.z = fmaxf(am.z, bm.z); am.w = fmaxf(am.w, bm.w);
        *(float4*)&lm[rl][c4] = am;
    }
    __syncthreads();
    if (rl < 2) {
        float4 a = *(float4*)&ls[rl][c4], bq = *(float4*)&ls[rl + 2][c4];
        a.x += bq.x; a.y += bq.y; a.z += bq.z; a.w += bq.w;
        *(float4*)&ls[rl][c4] = a;
        float4 am = *(float4*)&lm[rl][c4], bm = *(float4*)&lm[rl + 2][c4];
        am.x = fmaxf(am.x, bm.x); am.y = fmaxf(am.y, bm.y);
        am.z = fmaxf(am.z, bm.z); am.w = fmaxf(am.w, bm.w);
        *(float4*)&lm[rl][c4] = am;
    }
    __syncthreads();
    if (rl == 0) {
        float4 a = *(float4*)&ls[0][c4], bq = *(float4*)&ls[1][c4];
        a.x += bq.x; a.y += bq.y; a.z += bq.z; a.w += bq.w;
        *(float4*)(psum + (size_t)blockIdx.x * HID + c4) = a;
        float4 am = *(float4*)&lm[0][c4], bm = *(float4*)&lm[1][c4];
        am.x = fmaxf(am.x, bm.x); am.y = fmaxf(am.y, bm.y);
        am.z = fmaxf(am.z, bm.z); am.w = fmaxf(am.w, bm.w);
        *(float4*)(pmax + (size_t)blockIdx.x * HID + c4) = am;
    }
}

__global__ __launch_bounds__(1024) void k_reduce2(const float* __restrict__ psum, const float* __restrict__ pmax,
                                                  int nb, float* __restrict__ out, float invN) {
    __shared__ float ss[8][HID];
    __shared__ float sm[8][HID];
    int h = threadIdx.x & 127;
    int c = threadIdx.x >> 7;          // chunk 0..7
    int per = nb >> 3;
    float s = 0.f, m = -INFINITY;
    for (int b = c * per; b < (c + 1) * per; b++) {
        s += psum[b * HID + h];
        m = fmaxf(m, pmax[b * HID + h]);
    }
    ss[c][h] = s; sm[c][h] = m;
    __syncthreads();
    if (c < 4) { ss[c][h] += ss[c + 4][h]; sm[c][h] = fmaxf(sm[c][h], sm[c + 4][h]); }
    __syncthreads();
    if (c < 2) { ss[c][h] += ss[c + 2][h]; sm[c][h] = fmaxf(sm[c][h], sm[c + 2][h]); }
    __syncthreads();
    if (c == 0) {
        out[h] = (ss[0][h] + ss[1][h]) * invN;
        out[HID + h] = fmaxf(sm[0][h], sm[1][h]);
    }
}

// ---------------- Launch ----------------

extern "C" void kernel_launch(void* const* d_in, const int* in_sizes, int n_in,
                              void* d_out, int out_size, void* d_ws, size_t ws_size,
                              hipStream_t stream) {
    const float* nf    = (const float*)d_in[0];
    const int*   ei    = (const int*)d_in[1];
    const float* W_emb = (const float*)d_in[3];
    const float* b_emb = (const float*)d_in[4];
    const float* Wl    = (const float*)d_in[5];
    const float* bl    = (const float*)d_in[6];
    const float* Wr    = (const float*)d_in[7];
    const float* br    = (const float*)d_in[8];
    const float* att   = (const float*)d_in[9];
    const float* bias  = (const float*)d_in[10];

    const int N = in_sizes[0] / 11;
    const int E = in_sizes[1] / 2;
    const int* src = ei;
    const int* dst = ei + E;

    float* out  = (float*)d_out;
    float* xout = out + 2 * HID;

    // workspace carve-up
    char* w = (char*)d_ws;
    _Float16* xlh  = (_Float16*)w; w += (size_t)N * HID * 2;
    _Float16* xrh  = (_Float16*)w; w += (size_t)N * HID * 2;
    _Float16* xA   = (_Float16*)w; w += (size_t)N * HID * 2;
    _Float16* xB   = (_Float16*)w; w += (size_t)N * HID * 2;
    _Float16* WfL  = (_Float16*)w; w += (size_t)4 * HID * HID * 2;
    _Float16* WfR  = (_Float16*)w; w += (size_t)4 * HID * HID * 2;
    int*   gcnt    = (int*)w;   w += (size_t)256 * 4;
    int*   bstart  = (int*)w;   w += (size_t)256 * 4;
    int*   rowptr  = (int*)w;   w += (size_t)(N + 1) * 4;
    int*   arena   = (int*)w;   w += (size_t)256 * BCAP * 4;
    int*   csr_off = (int*)w;   w += (size_t)E * 4;
    float* psum    = (float*)w; w += (size_t)R1B * HID * 4;
    float* pmax    = (float*)w; w += (size_t)R1B * HID * 4;

    const int nbk = (N + 255) >> 8;       // 196 buckets
    const int nW = 4 * HID * HID;

    // weight fp16 conversion (both matrices, one launch)
    dim3 tg((nW / 4 + 255) / 256, 2);
    k_tof16<<<tg, 256, 0, stream>>>(Wl, Wr, WfL, WfR, nW);

    // CSR build (binned two-phase)
    k_zero_int<<<1, 256, 0, stream>>>(gcnt, 256);
    k_binA<<<(E + ACHUNK - 1) / ACHUNK, 256, 0, stream>>>(src, dst, E, gcnt, arena);
    k_scan_bk<<<1, 256, 0, stream>>>(gcnt, nbk, bstart, rowptr, N, E);
    k_binB<<<nbk, 256, 0, stream>>>(arena, gcnt, bstart, N, rowptr, csr_off);

    // embedding -> fp16 x (buffer A)
    k_embed<<<N, 128, 0, stream>>>(nf, W_emb, b_emb, xA, N);

    dim3 lgrid((N + 255) / 256, 2);
    for (int i = 0; i < 4; i++) {
        // ping-pong: even layers read A write B, odd layers read B write A
        const _Float16* xin = (i & 1) ? xB : xA;
        _Float16* xo        = (i & 1) ? xA : xB;
        k_linear_mfma<<<lgrid, 512, 0, stream>>>(xin,
                                                 WfL + (size_t)i * HID * HID, WfR + (size_t)i * HID * HID,
                                                 bl + i * HID, br + i * HID, xlh, xrh, N);
        k_attn<<<(N + 3) / 4, 256, 0, stream>>>(xlh, xrh, rowptr, csr_off,
                                                att + i * HEADS * 32, bias + i * HID,
                                                xin, xo, xout,
                                                i > 0 ? 1 : 0, i < 3 ? 1 : 0, N);
    }

    k_reduce1<<<R1B, 256, 0, stream>>>(xout, N, psum, pmax);
    k_reduce2<<<1, 1024, 0, stream>>>(psum, pmax, R1B, out, 1.0f / N);
}

// Round 5
// 389.263 us; speedup vs baseline: 1.0212x; 1.0212x over previous
//
#include <hip/hip_runtime.h>
#include <math.h>

#define HID 128
#define HEADS 4
#define NEG_SLOPE 0.2f
#define R1B 1024   // reduce1 grid
#define BCAP 8192  // per-bucket arena capacity (mean 4096, +64 sigma)
#define PB 6144    // binB LDS staging ints
#define ACHUNK 4096

typedef float f32x4 __attribute__((ext_vector_type(4)));
typedef _Float16 f16x8 __attribute__((ext_vector_type(8)));
typedef _Float16 f16x4 __attribute__((ext_vector_type(4)));
typedef _Float16 f16x2 __attribute__((ext_vector_type(2)));

#if defined(__has_builtin)
#if __has_builtin(__builtin_amdgcn_fdot2)
#define HAVE_FDOT2 1
#endif
#endif

// ---------------- CSR build: two-phase binned counting sort ----------------

// Phase A: bin 4096 edges/block into bucket arenas. Record = (src<<8)|(dst&255).
__global__ __launch_bounds__(256) void k_binA(const int* __restrict__ src, const int* __restrict__ dst,
                                              int E, int* __restrict__ gcnt, int* __restrict__ arena) {
    __shared__ int lh[256];
    __shared__ int lbase[256];
    __shared__ unsigned short lrank[ACHUNK];
    const int tid = threadIdx.x;
    lh[tid] = 0;
    __syncthreads();
    const int e0 = blockIdx.x * ACHUNK;
    #pragma unroll
    for (int i = 0; i < ACHUNK / 256; i++) {
        int e = e0 + i * 256 + tid;
        if (e < E) {
            int b = dst[e] >> 8;
            lrank[i * 256 + tid] = (unsigned short)atomicAdd(&lh[b], 1);
        }
    }
    __syncthreads();
    if (lh[tid] > 0) lbase[tid] = atomicAdd(&gcnt[tid], lh[tid]);
    __syncthreads();
    #pragma unroll
    for (int i = 0; i < ACHUNK / 256; i++) {
        int e = e0 + i * 256 + tid;
        if (e < E) {
            int d = dst[e];
            int b = d >> 8;
            arena[b * BCAP + lbase[b] + lrank[i * 256 + tid]] = (src[e] << 8) | (d & 255);
        }
    }
}

// Phase B: per bucket -- self-computed bucket prefix (scan of gcnt in LDS; kills
// the separate k_scan_bk launch), node counts + scan -> rowptr; staged,
// coalesced csr_off dump. csr_off value = src*256 = record & ~255.
__global__ __launch_bounds__(256) void k_binB(const int* __restrict__ arena, const int* __restrict__ gcnt,
                                              int N, int E,
                                              int* __restrict__ rowptr, int* __restrict__ csr_off) {
    __shared__ int ncnt[256];
    __shared__ int sbuf[256];
    __shared__ int nstart[256];
    __shared__ int exv[256];
    __shared__ int stage[PB];
    __shared__ unsigned short rk[BCAP];
    const int b = blockIdx.x, tid = threadIdx.x;

    // bucket-prefix scan (gcnt[tid]=0 for tid>=nbk, zeroed by k_tof16)
    int gv = gcnt[tid];
    sbuf[tid] = gv;
    __syncthreads();
    for (int off = 1; off < 256; off <<= 1) {
        int t = (tid >= off) ? sbuf[tid - off] : 0;
        __syncthreads();
        sbuf[tid] += t;
        __syncthreads();
    }
    exv[tid] = sbuf[tid] - gv;    // exclusive prefix
    if (b == 0 && tid == 0) rowptr[N] = E;
    __syncthreads();
    const int seg = exv[b];
    const int cnt = gcnt[b];

    ncnt[tid] = 0;
    __syncthreads();
    for (int k = tid; k < cnt; k += 256) {
        int v = arena[b * BCAP + k];
        rk[k] = (unsigned short)atomicAdd(&ncnt[v & 255], 1);
    }
    __syncthreads();
    int c = ncnt[tid];
    sbuf[tid] = c;
    __syncthreads();
    for (int off = 1; off < 256; off <<= 1) {
        int t = (tid >= off) ? sbuf[tid - off] : 0;
        __syncthreads();
        sbuf[tid] += t;
        __syncthreads();
    }
    int myStart = sbuf[tid] - c;   // exclusive
    nstart[tid] = myStart;
    int n = b * 256 + tid;
    if (n < N) rowptr[n] = seg + myStart;
    __syncthreads();
    for (int k = tid; k < cnt; k += 256) {
        int v = arena[b * BCAP + k];
        int pos = nstart[v & 255] + rk[k];
        int val = v & 0xFFFFFF00;
        if (pos < PB) stage[pos] = val;
        else          csr_off[seg + pos] = val;   // statistical overflow guard
    }
    __syncthreads();
    int lim = min(cnt, PB);
    for (int k = tid; k < lim; k += 256) csr_off[seg + k] = stage[k];
}

// ---------------- helpers ----------------

__device__ inline f16x2 absh2(f16x2 v) {
    unsigned u = __builtin_bit_cast(unsigned, v) & 0x7FFF7FFFu;
    return __builtin_bit_cast(f16x2, u);
}

__device__ inline f16x8 zero8() {
    f16x8 z;
    #pragma unroll
    for (int i = 0; i < 8; i++) z[i] = (_Float16)0.f;
    return z;
}

// quad_perm butterfly add via DPP (head groups are hardware quads).
template <int CTRL>
__device__ inline float qp_xor_add(float x) {
    int y = __builtin_amdgcn_update_dpp(0, __builtin_bit_cast(int, x),
                                        CTRL, 0xF, 0xF, true);
    return x + __builtin_bit_cast(float, y);
}

// per-edge logit: leaky_relu(xl+xr) . att  (packed fp16, fdot2 accumulate)
__device__ inline float edge_logit8(f16x8 c,
                                    f16x2 xr0, f16x2 xr1, f16x2 xr2, f16x2 xr3,
                                    f16x2 a0, f16x2 a1, f16x2 a2, f16x2 a3) {
    const f16x2 k06 = (f16x2){(_Float16)0.6f, (_Float16)0.6f};
    const f16x2 k04 = (f16x2){(_Float16)0.4f, (_Float16)0.4f};
    f16x2 c0 = __builtin_shufflevector(c, c, 0, 1);
    f16x2 c1 = __builtin_shufflevector(c, c, 2, 3);
    f16x2 c2 = __builtin_shufflevector(c, c, 4, 5);
    f16x2 c3 = __builtin_shufflevector(c, c, 6, 7);
    f16x2 u0 = c0 + xr0, u1 = c1 + xr1, u2 = c2 + xr2, u3 = c3 + xr3;
    f16x2 l0 = u0 * k06 + absh2(u0) * k04;   // leaky_relu, packed
    f16x2 l1 = u1 * k06 + absh2(u1) * k04;
    f16x2 l2 = u2 * k06 + absh2(u2) * k04;
    f16x2 l3 = u3 * k06 + absh2(u3) * k04;
#ifdef HAVE_FDOT2
    float p = __builtin_amdgcn_fdot2(l0, a0, 0.f, false);
    p = __builtin_amdgcn_fdot2(l1, a1, p, false);
    p = __builtin_amdgcn_fdot2(l2, a2, p, false);
    p = __builtin_amdgcn_fdot2(l3, a3, p, false);
#else
    float p = (float)l0[0] * (float)a0[0] + (float)l0[1] * (float)a0[1]
            + (float)l1[0] * (float)a1[0] + (float)l1[1] * (float)a1[1]
            + (float)l2[0] * (float)a2[0] + (float)l2[1] * (float)a2[1]
            + (float)l3[0] * (float)a3[0] + (float)l3[1] * (float)a3[1];
#endif
    return p;
}

// accumulate one weighted row into acc16[0..3] with LITERAL shuffle indices
#define ACC_ROW(WP, R)                                                        \
    acc16[0] += (WP) * __builtin_shufflevector((R), (R), 0, 1);               \
    acc16[1] += (WP) * __builtin_shufflevector((R), (R), 2, 3);               \
    acc16[2] += (WP) * __builtin_shufflevector((R), (R), 4, 5);               \
    acc16[3] += (WP) * __builtin_shufflevector((R), (R), 6, 7);

// fp32 -> fp16 convert for both W matrices in one launch (blockIdx.y selects).
// Block (0,0) also zeroes gcnt (runs before k_binA; kernel boundary orders it).
__global__ __launch_bounds__(256) void k_tof16(const float* __restrict__ a, const float* __restrict__ b,
                                               _Float16* __restrict__ oa, _Float16* __restrict__ ob,
                                               int* __restrict__ gcnt, int n) {
    if (blockIdx.x == 0 && blockIdx.y == 0) gcnt[threadIdx.x] = 0;
    const float* x = blockIdx.y ? b : a;
    _Float16*    o = blockIdx.y ? ob : oa;
    int base = (blockIdx.x * 256 + threadIdx.x) * 4;
    if (base >= n) return;
    float4 v = *(const float4*)(x + base);
    f16x4 h = {(_Float16)v.x, (_Float16)v.y, (_Float16)v.z, (_Float16)v.w};
    *(f16x4*)(o + base) = h;
}

// ---------------- MFMA linear, LDS-resident fp16 W, 2 A-tiles/wave ----------------

__global__ __launch_bounds__(512) void k_linear_mfma(
        const _Float16* __restrict__ xh,
        const _Float16* __restrict__ WfL, const _Float16* __restrict__ WfR,
        const float* __restrict__ bl, const float* __restrict__ br,
        _Float16* __restrict__ xlh, _Float16* __restrict__ xrh, int N) {
    __shared__ _Float16 lds[16384];   // 32 KB: W fp16, swizzled
    const int t   = threadIdx.x;
    const int mat = blockIdx.y;
    const _Float16* W = mat ? WfR : WfL;

    for (int g = t; g < 2048; g += 512) {
        int r = g >> 4, cc = g & 15;
        int dsto = r * 128 + ((cc ^ (r & 7)) << 3);      // half units
        *(float4*)&lds[dsto] = *(const float4*)(W + g * 8);
    }
    __syncthreads();

    const int wave = t >> 6;
    const int lane = t & 63;
    const int l16  = lane & 15;
    const int quad = lane >> 4;
    const int n0   = blockIdx.x * 256 + wave * 32;

    int arow0 = n0 + l16;
    int arow1 = n0 + 16 + l16;
    if (arow0 >= N) arow0 = N - 1;     // clamp loads; stores guarded below
    if (arow1 >= N) arow1 = N - 1;

    f32x4 acc[2][8];
    #pragma unroll
    for (int u = 0; u < 2; u++)
        #pragma unroll
        for (int s = 0; s < 8; s++) acc[u][s] = (f32x4){0.f, 0.f, 0.f, 0.f};

    #pragma unroll
    for (int k0 = 0; k0 < HID; k0 += 32) {
        f16x8 a0 = *(const f16x8*)(xh + arow0 * HID + k0 + quad * 8);
        f16x8 a1 = *(const f16x8*)(xh + arow1 * HID + k0 + quad * 8);
        const int cc = (k0 >> 3) + quad;
        #pragma unroll
        for (int s = 0; s < 8; s++) {
            const int row = s * 16 + l16;
            const int off = row * 128 + ((cc ^ (l16 & 7)) << 3);
            f16x8 b = *(const f16x8*)&lds[off];
            acc[0][s] = __builtin_amdgcn_mfma_f32_16x16x32_f16(a0, b, acc[0][s], 0, 0, 0);
            acc[1][s] = __builtin_amdgcn_mfma_f32_16x16x32_f16(a1, b, acc[1][s], 0, 0, 0);
        }
    }

    const float* bias = mat ? br : bl;
    _Float16* dst = mat ? xrh : xlh;
    #pragma unroll
    for (int s = 0; s < 8; s++) {
        int col = s * 16 + l16;
        float bv = bias[col];
        #pragma unroll
        for (int u = 0; u < 2; u++) {
            #pragma unroll
            for (int r = 0; r < 4; r++) {
                int node = n0 + u * 16 + quad * 4 + r;
                if (node < N) dst[(size_t)node * HID + col] = (_Float16)(acc[u][s][r] + bv);
            }
        }
    }
}

// ---------------- Fused attention: wave per node, 4 edge streams ----------------
// Round-4: eliminate wasted (clamp-duplicate) row gathers, which occupied VMEM
// queue slots (the kernel is MLP/queue-capped: depth-3 was neutral because at
// deg=16 the loop runs 2 iterations and clamped prefetch issued 10 row loads
// per 4 useful edges). Fast path deg<=16: straight-line, exactly the useful
// loads, pair-level predication (skipped pairs get zeroed regs so w=0 can't
// make 0*NaN). Slow path deg>=17: depth-2 pipeline with PREDICATED prefetch.

__global__ __launch_bounds__(256, 8) void k_attn(const _Float16* __restrict__ xlh, const _Float16* __restrict__ xrh,
                                              const int* __restrict__ rowptr, const int* __restrict__ csr_off,
                                              const float* __restrict__ att, const float* __restrict__ bias,
                                              const _Float16* __restrict__ xres, _Float16* __restrict__ outx,
                                              float* __restrict__ out,
                                              int add_res, int want_half, int N) {
    const int wave = threadIdx.x >> 6;
    const int lane = threadIdx.x & 63;
    const int strm = lane >> 4;          // edge stream 0..3
    const int l16  = lane & 15;          // channels [8*l16, 8*l16+8); head = l16>>2
    const int n = blockIdx.x * 4 + wave;
    if (n >= N) return;

    const float4 aA = *(const float4*)(att + 8 * l16);
    const float4 aB = *(const float4*)(att + 8 * l16 + 4);
    const f16x2 a0 = (f16x2){(_Float16)aA.x, (_Float16)aA.y};
    const f16x2 a1 = (f16x2){(_Float16)aA.z, (_Float16)aA.w};
    const f16x2 a2 = (f16x2){(_Float16)aB.x, (_Float16)aB.y};
    const f16x2 a3 = (f16x2){(_Float16)aB.z, (_Float16)aB.w};
    const f16x8 xrv = *(const f16x8*)(xrh + (size_t)n * HID + 8 * l16);
    const f16x2 xr0 = __builtin_shufflevector(xrv, xrv, 0, 1);
    const f16x2 xr1 = __builtin_shufflevector(xrv, xrv, 2, 3);
    const f16x2 xr2 = __builtin_shufflevector(xrv, xrv, 4, 5);
    const f16x2 xr3 = __builtin_shufflevector(xrv, xrv, 6, 7);
    const int s0 = rowptr[n], s1 = rowptr[n + 1];
    const int deg = s1 - s0;

    float den = 0.f;
    f16x2 acc16[4];
    #pragma unroll
    for (int q = 0; q < 4; q++) acc16[q] = (f16x2){(_Float16)0.f, (_Float16)0.f};

    const char* xlb = (const char*)xlh + l16 * 16;  // lane's 16B slice within a row
    const int j = s0 + 2 * strm;                    // stream's first edge

    if (deg > 0 && deg <= 16) {
        // ---- fast path: stream covers edges {j, j+1, j+8, j+9}; no loop ----
        const int last = s1 - 1;
        const int e0 = j, e1 = j + 1, e2 = j + 8, e3 = j + 9;
        f16x8 r0, r1, r2, r3;
        if (e0 < s1) {
            int o0 = csr_off[e0];
            int o1 = csr_off[min(e1, last)];
            r0 = *(const f16x8*)(xlb + o0);
            r1 = *(const f16x8*)(xlb + o1);
        } else { r0 = zero8(); r1 = zero8(); }
        if (e2 < s1) {
            int o2 = csr_off[e2];
            int o3 = csr_off[min(e3, last)];
            r2 = *(const f16x8*)(xlb + o2);
            r3 = *(const f16x8*)(xlb + o3);
        } else { r2 = zero8(); r3 = zero8(); }

        float p0 = edge_logit8(r0, xr0, xr1, xr2, xr3, a0, a1, a2, a3);
        float p1 = edge_logit8(r1, xr0, xr1, xr2, xr3, a0, a1, a2, a3);
        float p2 = edge_logit8(r2, xr0, xr1, xr2, xr3, a0, a1, a2, a3);
        float p3 = edge_logit8(r3, xr0, xr1, xr2, xr3, a0, a1, a2, a3);
        p0 = qp_xor_add<0xB1>(p0); p0 = qp_xor_add<0x4E>(p0);
        p1 = qp_xor_add<0xB1>(p1); p1 = qp_xor_add<0x4E>(p1);
        p2 = qp_xor_add<0xB1>(p2); p2 = qp_xor_add<0x4E>(p2);
        p3 = qp_xor_add<0xB1>(p3); p3 = qp_xor_add<0x4E>(p3);
        float w0 = (e0 < s1) ? __expf(p0) : 0.f;
        float w1 = (e1 < s1) ? __expf(p1) : 0.f;
        float w2 = (e2 < s1) ? __expf(p2) : 0.f;
        float w3 = (e3 < s1) ? __expf(p3) : 0.f;
        den += (w0 + w1) + (w2 + w3);
        f16x2 wp0 = (f16x2){(_Float16)w0, (_Float16)w0};
        f16x2 wp1 = (f16x2){(_Float16)w1, (_Float16)w1};
        f16x2 wp2 = (f16x2){(_Float16)w2, (_Float16)w2};
        f16x2 wp3 = (f16x2){(_Float16)w3, (_Float16)w3};
        ACC_ROW(wp0, r0)
        ACC_ROW(wp1, r1)
        ACC_ROW(wp2, r2)
        ACC_ROW(wp3, r3)
    } else if (deg > 16) {
        // ---- slow path: depth-2 pipeline, predicated prefetch ----
        const int last = s1 - 1;
        int jj = j;
        // prologue: all 4 rows valid (deg>=17 => j+9 <= s0+15 < s1)
        f16x8 pa0 = *(const f16x8*)(xlb + csr_off[jj]);
        f16x8 pb0 = *(const f16x8*)(xlb + csr_off[jj + 1]);
        f16x8 pa1 = *(const f16x8*)(xlb + csr_off[jj + 8]);
        f16x8 pb1 = *(const f16x8*)(xlb + csr_off[jj + 9]);
        int oa = csr_off[min(jj + 16, last)];
        int ob = csr_off[min(jj + 17, last)];
        while (jj < s1) {
            f16x8 ca = pa0, cb = pb0;
            pa0 = pa1; pb0 = pb1;
            if (jj + 16 < s1) {          // predicated prefetch: no dup gathers
                pa1 = *(const f16x8*)(xlb + oa);
                pb1 = *(const f16x8*)(xlb + ob);
                oa = csr_off[min(jj + 24, last)];
                ob = csr_off[min(jj + 25, last)];
            } else { pa1 = zero8(); pb1 = zero8(); }

            float pa = edge_logit8(ca, xr0, xr1, xr2, xr3, a0, a1, a2, a3);
            float pb = edge_logit8(cb, xr0, xr1, xr2, xr3, a0, a1, a2, a3);
            pa = qp_xor_add<0xB1>(pa); pa = qp_xor_add<0x4E>(pa);
            pb = qp_xor_add<0xB1>(pb); pb = qp_xor_add<0x4E>(pb);
            float wa = __expf(pa);
            float wb = (jj + 1 < s1) ? __expf(pb) : 0.f;
            den += wa + wb;
            f16x2 wpa = (f16x2){(_Float16)wa, (_Float16)wa};
            f16x2 wpb = (f16x2){(_Float16)wb, (_Float16)wb};
            ACC_ROW(wpa, ca)
            ACC_ROW(wpb, cb)
            jj += 8;
        }
    }

    // merge the four streams (lane stride 16/32) on packed f16x2
    den += __shfl_xor(den, 16);
    den += __shfl_xor(den, 32);
    #pragma unroll
    for (int q = 0; q < 4; q++) {
        float pk = __builtin_bit_cast(float, acc16[q]);
        acc16[q] += __builtin_bit_cast(f16x2, __shfl_xor(pk, 16));
        pk = __builtin_bit_cast(float, acc16[q]);
        acc16[q] += __builtin_bit_cast(f16x2, __shfl_xor(pk, 32));
    }

    if (strm == 0) {
        float acc[8];
        #pragma unroll
        for (int q = 0; q < 4; q++) {
            acc[2 * q]     = (float)acc16[q][0];
            acc[2 * q + 1] = (float)acc16[q][1];
        }
        float4 bA = *(const float4*)(bias + 8 * l16);
        float4 bB = *(const float4*)(bias + 8 * l16 + 4);
        float b[8] = {bA.x, bA.y, bA.z, bA.w, bB.x, bB.y, bB.z, bB.w};
        float inv = (den > 0.f) ? 1.f / den : 0.f;
        float v[8];
        #pragma unroll
        for (int q = 0; q < 8; q++) v[q] = fmaxf(acc[q] * inv + b[q], 0.f);
        if (add_res) {
            f16x8 r = *(const f16x8*)(xres + (size_t)n * HID + 8 * l16);
            #pragma unroll
            for (int q = 0; q < 8; q++) v[q] += (float)r[q];
        }
        if (want_half) {
            f16x8 h;
            #pragma unroll
            for (int q = 0; q < 8; q++) h[q] = (_Float16)v[q];
            *(f16x8*)(outx + (size_t)n * HID + 8 * l16) = h;
        } else {
            *(float4*)(out + (size_t)n * HID + 8 * l16)     = make_float4(v[0], v[1], v[2], v[3]);
            *(float4*)(out + (size_t)n * HID + 8 * l16 + 4) = make_float4(v[4], v[5], v[6], v[7]);
        }
    }
}

// ---------------- Embedding: x = relu(nf @ W_emb.T + b_emb) -> fp16 ----------------
// 2 nodes per 256-thread block (halves block count vs 128-thr/1-node).

__global__ __launch_bounds__(256) void k_embed(const float* __restrict__ nf, const float* __restrict__ W,
                                               const float* __restrict__ b,
                                               _Float16* __restrict__ xh, int N) {
    __shared__ float f[2][11];
    const int sub = threadIdx.x >> 7;
    const int h   = threadIdx.x & 127;
    const int n   = blockIdx.x * 2 + sub;
    if (n < N && h < 11) f[sub][h] = nf[(size_t)n * 11 + h];
    __syncthreads();
    if (n >= N) return;
    float acc = b[h];
    #pragma unroll
    for (int k = 0; k < 11; k++) acc += f[sub][k] * W[h * 11 + k];
    xh[(size_t)n * HID + h] = (_Float16)fmaxf(acc, 0.f);
}

// ---------------- Graph readout: mean + max over nodes ----------------

__global__ __launch_bounds__(256) void k_reduce1(const float* __restrict__ x, int N,
                                                 float* __restrict__ psum, float* __restrict__ pmax) {
    __shared__ float ls[8][HID];
    __shared__ float lm[8][HID];
    const int c4 = (threadIdx.x & 31) << 2;   // channel base
    const int rl = threadIdx.x >> 5;          // row lane 0..7
    const int per = (N + gridDim.x - 1) / gridDim.x;
    const int n0 = blockIdx.x * per, n1 = min(N, n0 + per);
    float4 s = make_float4(0.f, 0.f, 0.f, 0.f);
    float4 m = make_float4(-INFINITY, -INFINITY, -INFINITY, -INFINITY);
    for (int n = n0 + rl; n < n1; n += 8) {
        float4 v = *(const float4*)(x + (size_t)n * HID + c4);
        s.x += v.x; s.y += v.y; s.z += v.z; s.w += v.w;
        m.x = fmaxf(m.x, v.x); m.y = fmaxf(m.y, v.y);
        m.z = fmaxf(m.z, v.z); m.w = fmaxf(m.w, v.w);
    }
    *(float4*)&ls[rl][c4] = s;
    *(float4*)&lm[rl][c4] = m;
    __syncthreads();
    if (rl < 4) {
        float4 a = *(float4*)&ls[rl][c4], bq = *(float4*)&ls[rl + 4][c4];
        a.x += bq.x; a.y += bq.y; a.z += bq.z; a.w += bq.w;
        *(float4*)&ls[rl][c4] = a;
        float4 am = *(float4*)&lm[rl][c4], bm = *(float4*)&lm[rl + 4][c4];
        am.x = fmaxf(am.x, bm.x); am.y = fmaxf(am.y, bm.y);
        am.z = fmaxf(am.z, bm.z); am.w = fmaxf(am.w, bm.w);
        *(float4*)&lm[rl][c4] = am;
    }
    __syncthreads();
    if (rl < 2) {
        float4 a = *(float4*)&ls[rl][c4], bq = *(float4*)&ls[rl + 2][c4];
        a.x += bq.x; a.y += bq.y; a.z += bq.z; a.w += bq.w;
        *(float4*)&ls[rl][c4] = a;
        float4 am = *(float4*)&lm[rl][c4], bm = *(float4*)&lm[rl + 2][c4];
        am.x = fmaxf(am.x, bm.x); am.y = fmaxf(am.y, bm.y);
        am.z = fmaxf(am.z, bm.z); am.w = fmaxf(am.w, bm.w);
        *(float4*)&lm[rl][c4] = am;
    }
    __syncthreads();
    if (rl == 0) {
        float4 a = *(float4*)&ls[0][c4], bq = *(float4*)&ls[1][c4];
        a.x += bq.x; a.y += bq.y; a.z += bq.z; a.w += bq.w;
        *(float4*)(psum + (size_t)blockIdx.x * HID + c4) = a;
        float4 am = *(float4*)&lm[0][c4], bm = *(float4*)&lm[1][c4];
        am.x = fmaxf(am.x, bm.x); am.y = fmaxf(am.y, bm.y);
        am.z = fmaxf(am.z, bm.z); am.w = fmaxf(am.w, bm.w);
        *(float4*)(pmax + (size_t)blockIdx.x * HID + c4) = am;
    }
}

__global__ __launch_bounds__(1024) void k_reduce2(const float* __restrict__ psum, const float* __restrict__ pmax,
                                                  int nb, float* __restrict__ out, float invN) {
    __shared__ float ss[8][HID];
    __shared__ float sm[8][HID];
    int h = threadIdx.x & 127;
    int c = threadIdx.x >> 7;          // chunk 0..7
    int per = nb >> 3;
    float s = 0.f, m = -INFINITY;
    for (int b = c * per; b < (c + 1) * per; b++) {
        s += psum[b * HID + h];
        m = fmaxf(m, pmax[b * HID + h]);
    }
    ss[c][h] = s; sm[c][h] = m;
    __syncthreads();
    if (c < 4) { ss[c][h] += ss[c + 4][h]; sm[c][h] = fmaxf(sm[c][h], sm[c + 4][h]); }
    __syncthreads();
    if (c < 2) { ss[c][h] += ss[c + 2][h]; sm[c][h] = fmaxf(sm[c][h], sm[c + 2][h]); }
    __syncthreads();
    if (c == 0) {
        out[h] = (ss[0][h] + ss[1][h]) * invN;
        out[HID + h] = fmaxf(sm[0][h], sm[1][h]);
    }
}

// ---------------- Launch ----------------

extern "C" void kernel_launch(void* const* d_in, const int* in_sizes, int n_in,
                              void* d_out, int out_size, void* d_ws, size_t ws_size,
                              hipStream_t stream) {
    const float* nf    = (const float*)d_in[0];
    const int*   ei    = (const int*)d_in[1];
    const float* W_emb = (const float*)d_in[3];
    const float* b_emb = (const float*)d_in[4];
    const float* Wl    = (const float*)d_in[5];
    const float* bl    = (const float*)d_in[6];
    const float* Wr    = (const float*)d_in[7];
    const float* br    = (const float*)d_in[8];
    const float* att   = (const float*)d_in[9];
    const float* bias  = (const float*)d_in[10];

    const int N = in_sizes[0] / 11;
    const int E = in_sizes[1] / 2;
    const int* src = ei;
    const int* dst = ei + E;

    float* out  = (float*)d_out;
    float* xout = out + 2 * HID;

    // workspace carve-up
    char* w = (char*)d_ws;
    _Float16* xlh  = (_Float16*)w; w += (size_t)N * HID * 2;
    _Float16* xrh  = (_Float16*)w; w += (size_t)N * HID * 2;
    _Float16* xA   = (_Float16*)w; w += (size_t)N * HID * 2;
    _Float16* xB   = (_Float16*)w; w += (size_t)N * HID * 2;
    _Float16* WfL  = (_Float16*)w; w += (size_t)4 * HID * HID * 2;
    _Float16* WfR  = (_Float16*)w; w += (size_t)4 * HID * HID * 2;
    int*   gcnt    = (int*)w;   w += (size_t)256 * 4;
    int*   rowptr  = (int*)w;   w += (size_t)(N + 1) * 4;
    int*   arena   = (int*)w;   w += (size_t)256 * BCAP * 4;
    int*   csr_off = (int*)w;   w += (size_t)E * 4;
    float* psum    = (float*)w; w += (size_t)R1B * HID * 4;
    float* pmax    = (float*)w; w += (size_t)R1B * HID * 4;

    const int nbk = (N + 255) >> 8;       // 196 buckets
    const int nW = 4 * HID * HID;

    // weight fp16 conversion (both matrices) + gcnt zeroing, one launch
    dim3 tg((nW / 4 + 255) / 256, 2);
    k_tof16<<<tg, 256, 0, stream>>>(Wl, Wr, WfL, WfR, gcnt, nW);

    // CSR build (binned two-phase; binB self-scans bucket prefix)
    k_binA<<<(E + ACHUNK - 1) / ACHUNK, 256, 0, stream>>>(src, dst, E, gcnt, arena);
    k_binB<<<nbk, 256, 0, stream>>>(arena, gcnt, N, E, rowptr, csr_off);

    // embedding -> fp16 x (buffer A)
    k_embed<<<(N + 1) / 2, 256, 0, stream>>>(nf, W_emb, b_emb, xA, N);

    dim3 lgrid((N + 255) / 256, 2);
    for (int i = 0; i < 4; i++) {
        // ping-pong: even layers read A write B, odd layers read B write A
        const _Float16* xin = (i & 1) ? xB : xA;
        _Float16* xo        = (i & 1) ? xA : xB;
        k_linear_mfma<<<lgrid, 512, 0, stream>>>(xin,
                                                 WfL + (size_t)i * HID * HID, WfR + (size_t)i * HID * HID,
                                                 bl + i * HID, br + i * HID, xlh, xrh, N);
        k_attn<<<(N + 3) / 4, 256, 0, stream>>>(xlh, xrh, rowptr, csr_off,
                                                att + i * HEADS * 32, bias + i * HID,
                                                xin, xo, xout,
                                                i > 0 ? 1 : 0, i < 3 ? 1 : 0, N);
    }

    k_reduce1<<<R1B, 256, 0, stream>>>(xout, N, psum, pmax);
    k_reduce2<<<1, 1024, 0, stream>>>(psum, pmax, R1B, out, 1.0f / N);
}

// Round 6
// 373.941 us; speedup vs baseline: 1.0630x; 1.0410x over previous
//
#include <hip/hip_runtime.h>
#include <math.h>

#define HID 128
#define HEADS 4
#define NEG_SLOPE 0.2f
#define R1B 1024   // reduce1 grid
#define BCAP 8192  // per-bucket arena capacity (mean 4096, +64 sigma)
#define PB 6144    // binB LDS staging ints
#define ACHUNK 4096

typedef float f32x4 __attribute__((ext_vector_type(4)));
typedef _Float16 f16x8 __attribute__((ext_vector_type(8)));
typedef _Float16 f16x4 __attribute__((ext_vector_type(4)));
typedef _Float16 f16x2 __attribute__((ext_vector_type(2)));

#if defined(__has_builtin)
#if __has_builtin(__builtin_amdgcn_fdot2)
#define HAVE_FDOT2 1
#endif
#endif

// ---------------- CSR build: two-phase binned counting sort ----------------

// Phase A: bin 4096 edges/block into bucket arenas. Record = (src<<8)|(dst&255).
__global__ __launch_bounds__(256) void k_binA(const int* __restrict__ src, const int* __restrict__ dst,
                                              int E, int* __restrict__ gcnt, int* __restrict__ arena) {
    __shared__ int lh[256];
    __shared__ int lbase[256];
    __shared__ unsigned short lrank[ACHUNK];
    const int tid = threadIdx.x;
    lh[tid] = 0;
    __syncthreads();
    const int e0 = blockIdx.x * ACHUNK;
    #pragma unroll
    for (int i = 0; i < ACHUNK / 256; i++) {
        int e = e0 + i * 256 + tid;
        if (e < E) {
            int b = dst[e] >> 8;
            lrank[i * 256 + tid] = (unsigned short)atomicAdd(&lh[b], 1);
        }
    }
    __syncthreads();
    if (lh[tid] > 0) lbase[tid] = atomicAdd(&gcnt[tid], lh[tid]);
    __syncthreads();
    #pragma unroll
    for (int i = 0; i < ACHUNK / 256; i++) {
        int e = e0 + i * 256 + tid;
        if (e < E) {
            int d = dst[e];
            int b = d >> 8;
            arena[b * BCAP + lbase[b] + lrank[i * 256 + tid]] = (src[e] << 8) | (d & 255);
        }
    }
}

// Phase B: per bucket -- self-computed bucket prefix, node counts + scan ->
// rowptr; staged, coalesced csr_off dump. csr_off value = src*256.
__global__ __launch_bounds__(256) void k_binB(const int* __restrict__ arena, const int* __restrict__ gcnt,
                                              int N, int E,
                                              int* __restrict__ rowptr, int* __restrict__ csr_off) {
    __shared__ int ncnt[256];
    __shared__ int sbuf[256];
    __shared__ int nstart[256];
    __shared__ int exv[256];
    __shared__ int stage[PB];
    __shared__ unsigned short rk[BCAP];
    const int b = blockIdx.x, tid = threadIdx.x;

    // bucket-prefix scan (gcnt[tid]=0 for tid>=nbk, zeroed by k_tof16)
    int gv = gcnt[tid];
    sbuf[tid] = gv;
    __syncthreads();
    for (int off = 1; off < 256; off <<= 1) {
        int t = (tid >= off) ? sbuf[tid - off] : 0;
        __syncthreads();
        sbuf[tid] += t;
        __syncthreads();
    }
    exv[tid] = sbuf[tid] - gv;    // exclusive prefix
    if (b == 0 && tid == 0) rowptr[N] = E;
    __syncthreads();
    const int seg = exv[b];
    const int cnt = gcnt[b];

    ncnt[tid] = 0;
    __syncthreads();
    for (int k = tid; k < cnt; k += 256) {
        int v = arena[b * BCAP + k];
        rk[k] = (unsigned short)atomicAdd(&ncnt[v & 255], 1);
    }
    __syncthreads();
    int c = ncnt[tid];
    sbuf[tid] = c;
    __syncthreads();
    for (int off = 1; off < 256; off <<= 1) {
        int t = (tid >= off) ? sbuf[tid - off] : 0;
        __syncthreads();
        sbuf[tid] += t;
        __syncthreads();
    }
    int myStart = sbuf[tid] - c;   // exclusive
    nstart[tid] = myStart;
    int n = b * 256 + tid;
    if (n < N) rowptr[n] = seg + myStart;
    __syncthreads();
    for (int k = tid; k < cnt; k += 256) {
        int v = arena[b * BCAP + k];
        int pos = nstart[v & 255] + rk[k];
        int val = v & 0xFFFFFF00;
        if (pos < PB) stage[pos] = val;
        else          csr_off[seg + pos] = val;   // statistical overflow guard
    }
    __syncthreads();
    int lim = min(cnt, PB);
    for (int k = tid; k < lim; k += 256) csr_off[seg + k] = stage[k];
}

// ---------------- helpers ----------------

__device__ inline f16x2 absh2(f16x2 v) {
    unsigned u = __builtin_bit_cast(unsigned, v) & 0x7FFF7FFFu;
    return __builtin_bit_cast(f16x2, u);
}

__device__ inline f16x8 zero8() {
    f16x8 z;
    #pragma unroll
    for (int i = 0; i < 8; i++) z[i] = (_Float16)0.f;
    return z;
}

// quad_perm butterfly add via DPP (head groups are hardware quads).
template <int CTRL>
__device__ inline float qp_xor_add(float x) {
    int y = __builtin_amdgcn_update_dpp(0, __builtin_bit_cast(int, x),
                                        CTRL, 0xF, 0xF, true);
    return x + __builtin_bit_cast(float, y);
}

// per-edge logit: leaky_relu(xl+xr) . att  (packed fp16, fdot2 accumulate)
__device__ inline float edge_logit8(f16x8 c,
                                    f16x2 xr0, f16x2 xr1, f16x2 xr2, f16x2 xr3,
                                    f16x2 a0, f16x2 a1, f16x2 a2, f16x2 a3) {
    const f16x2 k06 = (f16x2){(_Float16)0.6f, (_Float16)0.6f};
    const f16x2 k04 = (f16x2){(_Float16)0.4f, (_Float16)0.4f};
    f16x2 c0 = __builtin_shufflevector(c, c, 0, 1);
    f16x2 c1 = __builtin_shufflevector(c, c, 2, 3);
    f16x2 c2 = __builtin_shufflevector(c, c, 4, 5);
    f16x2 c3 = __builtin_shufflevector(c, c, 6, 7);
    f16x2 u0 = c0 + xr0, u1 = c1 + xr1, u2 = c2 + xr2, u3 = c3 + xr3;
    f16x2 l0 = u0 * k06 + absh2(u0) * k04;   // leaky_relu, packed
    f16x2 l1 = u1 * k06 + absh2(u1) * k04;
    f16x2 l2 = u2 * k06 + absh2(u2) * k04;
    f16x2 l3 = u3 * k06 + absh2(u3) * k04;
#ifdef HAVE_FDOT2
    float p = __builtin_amdgcn_fdot2(l0, a0, 0.f, false);
    p = __builtin_amdgcn_fdot2(l1, a1, p, false);
    p = __builtin_amdgcn_fdot2(l2, a2, p, false);
    p = __builtin_amdgcn_fdot2(l3, a3, p, false);
#else
    float p = (float)l0[0] * (float)a0[0] + (float)l0[1] * (float)a0[1]
            + (float)l1[0] * (float)a1[0] + (float)l1[1] * (float)a1[1]
            + (float)l2[0] * (float)a2[0] + (float)l2[1] * (float)a2[1]
            + (float)l3[0] * (float)a3[0] + (float)l3[1] * (float)a3[1];
#endif
    return p;
}

// accumulate one weighted row into acc16[0..3] with LITERAL shuffle indices
#define ACC_ROW(WP, R)                                                        \
    acc16[0] += (WP) * __builtin_shufflevector((R), (R), 0, 1);               \
    acc16[1] += (WP) * __builtin_shufflevector((R), (R), 2, 3);               \
    acc16[2] += (WP) * __builtin_shufflevector((R), (R), 4, 5);               \
    acc16[3] += (WP) * __builtin_shufflevector((R), (R), 6, 7);

// fp32 -> fp16 convert for both W matrices in one launch (blockIdx.y selects).
// Block (0,0) also zeroes gcnt (runs before k_binA; kernel boundary orders it).
__global__ __launch_bounds__(256) void k_tof16(const float* __restrict__ a, const float* __restrict__ b,
                                               _Float16* __restrict__ oa, _Float16* __restrict__ ob,
                                               int* __restrict__ gcnt, int n) {
    if (blockIdx.x == 0 && blockIdx.y == 0) gcnt[threadIdx.x] = 0;
    const float* x = blockIdx.y ? b : a;
    _Float16*    o = blockIdx.y ? ob : oa;
    int base = (blockIdx.x * 256 + threadIdx.x) * 4;
    if (base >= n) return;
    float4 v = *(const float4*)(x + base);
    f16x4 h = {(_Float16)v.x, (_Float16)v.y, (_Float16)v.z, (_Float16)v.w};
    *(f16x4*)(o + base) = h;
}

// ---------------- MFMA linear, LDS-resident fp16 W, 2 A-tiles/wave ----------------
// Round-6: epilogue routed through LDS. The old epilogue issued 64 scalar
// 2B stores/lane (32B segments 1KB apart) -> WRITE_SIZE 42.4MB vs 25.6 ideal
// (1.66x amplification). Now: after the k-loop, two rounds (waves 0-3, 4-7)
// write their C-tiles into the (consumed) W LDS buffer with node stride 136
// halves (breaks quad bank aliasing), then the whole block dumps 32KB with
// coalesced 16B/lane loads+stores. LDS = 34.8KB, occupancy unchanged.

__global__ __launch_bounds__(512) void k_linear_mfma(
        const _Float16* __restrict__ xh,
        const _Float16* __restrict__ WfL, const _Float16* __restrict__ WfR,
        const float* __restrict__ bl, const float* __restrict__ br,
        _Float16* __restrict__ xlh, _Float16* __restrict__ xrh, int N) {
    __shared__ _Float16 lds[17408];   // max(W 16384, transpose 128x136)
    const int t   = threadIdx.x;
    const int mat = blockIdx.y;
    const _Float16* W = mat ? WfR : WfL;

    for (int g = t; g < 2048; g += 512) {
        int r = g >> 4, cc = g & 15;
        int dsto = r * 128 + ((cc ^ (r & 7)) << 3);      // half units
        *(float4*)&lds[dsto] = *(const float4*)(W + g * 8);
    }
    __syncthreads();

    const int wave = t >> 6;
    const int lane = t & 63;
    const int l16  = lane & 15;
    const int quad = lane >> 4;
    const int n0   = blockIdx.x * 256 + wave * 32;

    int arow0 = n0 + l16;
    int arow1 = n0 + 16 + l16;
    if (arow0 >= N) arow0 = N - 1;     // clamp loads; stores guarded below
    if (arow1 >= N) arow1 = N - 1;

    f32x4 acc[2][8];
    #pragma unroll
    for (int u = 0; u < 2; u++)
        #pragma unroll
        for (int s = 0; s < 8; s++) acc[u][s] = (f32x4){0.f, 0.f, 0.f, 0.f};

    #pragma unroll
    for (int k0 = 0; k0 < HID; k0 += 32) {
        f16x8 a0 = *(const f16x8*)(xh + arow0 * HID + k0 + quad * 8);
        f16x8 a1 = *(const f16x8*)(xh + arow1 * HID + k0 + quad * 8);
        const int cc = (k0 >> 3) + quad;
        #pragma unroll
        for (int s = 0; s < 8; s++) {
            const int row = s * 16 + l16;
            const int off = row * 128 + ((cc ^ (l16 & 7)) << 3);
            f16x8 b = *(const f16x8*)&lds[off];
            acc[0][s] = __builtin_amdgcn_mfma_f32_16x16x32_f16(a0, b, acc[0][s], 0, 0, 0);
            acc[1][s] = __builtin_amdgcn_mfma_f32_16x16x32_f16(a1, b, acc[1][s], 0, 0, 0);
        }
    }

    const float* bias = mat ? br : bl;
    _Float16* dst = mat ? xrh : xlh;
    const int wl = wave & 3;            // wave index within a round

    #pragma unroll
    for (int round = 0; round < 2; round++) {
        __syncthreads();                 // W (or previous round) fully consumed
        if ((wave >> 2) == round) {
            #pragma unroll
            for (int s = 0; s < 8; s++) {
                int col = s * 16 + l16;
                float bv = bias[col];
                #pragma unroll
                for (int u = 0; u < 2; u++) {
                    #pragma unroll
                    for (int r = 0; r < 4; r++) {
                        int nd = wl * 32 + u * 16 + quad * 4 + r;   // 0..127
                        lds[nd * 136 + col] = (_Float16)(acc[u][s][r] + bv);
                    }
                }
            }
        }
        __syncthreads();
        // coalesced dump: 128 nodes x 256B = 2048 x 16B units
        const int base_node = blockIdx.x * 256 + round * 128;
        #pragma unroll
        for (int it = 0; it < 4; it++) {
            int idx = it * 512 + t;
            int node = base_node + (idx >> 4);
            if (node < N)
                *(float4*)(dst + (size_t)node * HID + (idx & 15) * 8) =
                    *(float4*)&lds[(idx >> 4) * 136 + (idx & 15) * 8];
        }
    }
}

// ---------------- Fused attention: wave per node, 4 edge streams ----------------
// Fast path deg<=16: straight-line, exactly the useful loads, pair-level
// predication. Slow path deg>=17: depth-2 pipeline with predicated prefetch.

__global__ __launch_bounds__(256, 8) void k_attn(const _Float16* __restrict__ xlh, const _Float16* __restrict__ xrh,
                                              const int* __restrict__ rowptr, const int* __restrict__ csr_off,
                                              const float* __restrict__ att, const float* __restrict__ bias,
                                              const _Float16* __restrict__ xres, _Float16* __restrict__ outx,
                                              float* __restrict__ out,
                                              int add_res, int want_half, int N) {
    const int wave = threadIdx.x >> 6;
    const int lane = threadIdx.x & 63;
    const int strm = lane >> 4;          // edge stream 0..3
    const int l16  = lane & 15;          // channels [8*l16, 8*l16+8); head = l16>>2
    const int n = blockIdx.x * 4 + wave;
    if (n >= N) return;

    const float4 aA = *(const float4*)(att + 8 * l16);
    const float4 aB = *(const float4*)(att + 8 * l16 + 4);
    const f16x2 a0 = (f16x2){(_Float16)aA.x, (_Float16)aA.y};
    const f16x2 a1 = (f16x2){(_Float16)aA.z, (_Float16)aA.w};
    const f16x2 a2 = (f16x2){(_Float16)aB.x, (_Float16)aB.y};
    const f16x2 a3 = (f16x2){(_Float16)aB.z, (_Float16)aB.w};
    const f16x8 xrv = *(const f16x8*)(xrh + (size_t)n * HID + 8 * l16);
    const f16x2 xr0 = __builtin_shufflevector(xrv, xrv, 0, 1);
    const f16x2 xr1 = __builtin_shufflevector(xrv, xrv, 2, 3);
    const f16x2 xr2 = __builtin_shufflevector(xrv, xrv, 4, 5);
    const f16x2 xr3 = __builtin_shufflevector(xrv, xrv, 6, 7);
    const int s0 = rowptr[n], s1 = rowptr[n + 1];
    const int deg = s1 - s0;

    float den = 0.f;
    f16x2 acc16[4];
    #pragma unroll
    for (int q = 0; q < 4; q++) acc16[q] = (f16x2){(_Float16)0.f, (_Float16)0.f};

    const char* xlb = (const char*)xlh + l16 * 16;  // lane's 16B slice within a row
    const int j = s0 + 2 * strm;                    // stream's first edge

    if (deg > 0 && deg <= 16) {
        // ---- fast path: stream covers edges {j, j+1, j+8, j+9}; no loop ----
        const int last = s1 - 1;
        const int e0 = j, e1 = j + 1, e2 = j + 8, e3 = j + 9;
        f16x8 r0, r1, r2, r3;
        if (e0 < s1) {
            int o0 = csr_off[e0];
            int o1 = csr_off[min(e1, last)];
            r0 = *(const f16x8*)(xlb + o0);
            r1 = *(const f16x8*)(xlb + o1);
        } else { r0 = zero8(); r1 = zero8(); }
        if (e2 < s1) {
            int o2 = csr_off[e2];
            int o3 = csr_off[min(e3, last)];
            r2 = *(const f16x8*)(xlb + o2);
            r3 = *(const f16x8*)(xlb + o3);
        } else { r2 = zero8(); r3 = zero8(); }

        float p0 = edge_logit8(r0, xr0, xr1, xr2, xr3, a0, a1, a2, a3);
        float p1 = edge_logit8(r1, xr0, xr1, xr2, xr3, a0, a1, a2, a3);
        float p2 = edge_logit8(r2, xr0, xr1, xr2, xr3, a0, a1, a2, a3);
        float p3 = edge_logit8(r3, xr0, xr1, xr2, xr3, a0, a1, a2, a3);
        p0 = qp_xor_add<0xB1>(p0); p0 = qp_xor_add<0x4E>(p0);
        p1 = qp_xor_add<0xB1>(p1); p1 = qp_xor_add<0x4E>(p1);
        p2 = qp_xor_add<0xB1>(p2); p2 = qp_xor_add<0x4E>(p2);
        p3 = qp_xor_add<0xB1>(p3); p3 = qp_xor_add<0x4E>(p3);
        float w0 = (e0 < s1) ? __expf(p0) : 0.f;
        float w1 = (e1 < s1) ? __expf(p1) : 0.f;
        float w2 = (e2 < s1) ? __expf(p2) : 0.f;
        float w3 = (e3 < s1) ? __expf(p3) : 0.f;
        den += (w0 + w1) + (w2 + w3);
        f16x2 wp0 = (f16x2){(_Float16)w0, (_Float16)w0};
        f16x2 wp1 = (f16x2){(_Float16)w1, (_Float16)w1};
        f16x2 wp2 = (f16x2){(_Float16)w2, (_Float16)w2};
        f16x2 wp3 = (f16x2){(_Float16)w3, (_Float16)w3};
        ACC_ROW(wp0, r0)
        ACC_ROW(wp1, r1)
        ACC_ROW(wp2, r2)
        ACC_ROW(wp3, r3)
    } else if (deg > 16) {
        // ---- slow path: depth-2 pipeline, predicated prefetch ----
        const int last = s1 - 1;
        int jj = j;
        // prologue: all 4 rows valid (deg>=17 => j+9 <= s0+15 < s1)
        f16x8 pa0 = *(const f16x8*)(xlb + csr_off[jj]);
        f16x8 pb0 = *(const f16x8*)(xlb + csr_off[jj + 1]);
        f16x8 pa1 = *(const f16x8*)(xlb + csr_off[jj + 8]);
        f16x8 pb1 = *(const f16x8*)(xlb + csr_off[jj + 9]);
        int oa = csr_off[min(jj + 16, last)];
        int ob = csr_off[min(jj + 17, last)];
        while (jj < s1) {
            f16x8 ca = pa0, cb = pb0;
            pa0 = pa1; pb0 = pb1;
            if (jj + 16 < s1) {          // predicated prefetch: no dup gathers
                pa1 = *(const f16x8*)(xlb + oa);
                pb1 = *(const f16x8*)(xlb + ob);
                oa = csr_off[min(jj + 24, last)];
                ob = csr_off[min(jj + 25, last)];
            } else { pa1 = zero8(); pb1 = zero8(); }

            float pa = edge_logit8(ca, xr0, xr1, xr2, xr3, a0, a1, a2, a3);
            float pb = edge_logit8(cb, xr0, xr1, xr2, xr3, a0, a1, a2, a3);
            pa = qp_xor_add<0xB1>(pa); pa = qp_xor_add<0x4E>(pa);
            pb = qp_xor_add<0xB1>(pb); pb = qp_xor_add<0x4E>(pb);
            float wa = __expf(pa);
            float wb = (jj + 1 < s1) ? __expf(pb) : 0.f;
            den += wa + wb;
            f16x2 wpa = (f16x2){(_Float16)wa, (_Float16)wa};
            f16x2 wpb = (f16x2){(_Float16)wb, (_Float16)wb};
            ACC_ROW(wpa, ca)
            ACC_ROW(wpb, cb)
            jj += 8;
        }
    }

    // merge the four streams (lane stride 16/32) on packed f16x2
    den += __shfl_xor(den, 16);
    den += __shfl_xor(den, 32);
    #pragma unroll
    for (int q = 0; q < 4; q++) {
        float pk = __builtin_bit_cast(float, acc16[q]);
        acc16[q] += __builtin_bit_cast(f16x2, __shfl_xor(pk, 16));
        pk = __builtin_bit_cast(float, acc16[q]);
        acc16[q] += __builtin_bit_cast(f16x2, __shfl_xor(pk, 32));
    }

    if (strm == 0) {
        float acc[8];
        #pragma unroll
        for (int q = 0; q < 4; q++) {
            acc[2 * q]     = (float)acc16[q][0];
            acc[2 * q + 1] = (float)acc16[q][1];
        }
        float4 bA = *(const float4*)(bias + 8 * l16);
        float4 bB = *(const float4*)(bias + 8 * l16 + 4);
        float b[8] = {bA.x, bA.y, bA.z, bA.w, bB.x, bB.y, bB.z, bB.w};
        float inv = (den > 0.f) ? 1.f / den : 0.f;
        float v[8];
        #pragma unroll
        for (int q = 0; q < 8; q++) v[q] = fmaxf(acc[q] * inv + b[q], 0.f);
        if (add_res) {
            f16x8 r = *(const f16x8*)(xres + (size_t)n * HID + 8 * l16);
            #pragma unroll
            for (int q = 0; q < 8; q++) v[q] += (float)r[q];
        }
        if (want_half) {
            f16x8 h;
            #pragma unroll
            for (int q = 0; q < 8; q++) h[q] = (_Float16)v[q];
            *(f16x8*)(outx + (size_t)n * HID + 8 * l16) = h;
        } else {
            *(float4*)(out + (size_t)n * HID + 8 * l16)     = make_float4(v[0], v[1], v[2], v[3]);
            *(float4*)(out + (size_t)n * HID + 8 * l16 + 4) = make_float4(v[4], v[5], v[6], v[7]);
        }
    }
}

// ---------------- Embedding: x = relu(nf @ W_emb.T + b_emb) -> fp16 ----------------
// 2 nodes per 256-thread block.

__global__ __launch_bounds__(256) void k_embed(const float* __restrict__ nf, const float* __restrict__ W,
                                               const float* __restrict__ b,
                                               _Float16* __restrict__ xh, int N) {
    __shared__ float f[2][11];
    const int sub = threadIdx.x >> 7;
    const int h   = threadIdx.x & 127;
    const int n   = blockIdx.x * 2 + sub;
    if (n < N && h < 11) f[sub][h] = nf[(size_t)n * 11 + h];
    __syncthreads();
    if (n >= N) return;
    float acc = b[h];
    #pragma unroll
    for (int k = 0; k < 11; k++) acc += f[sub][k] * W[h * 11 + k];
    xh[(size_t)n * HID + h] = (_Float16)fmaxf(acc, 0.f);
}

// ---------------- Graph readout: mean + max over nodes ----------------

__global__ __launch_bounds__(256) void k_reduce1(const float* __restrict__ x, int N,
                                                 float* __restrict__ psum, float* __restrict__ pmax) {
    __shared__ float ls[8][HID];
    __shared__ float lm[8][HID];
    const int c4 = (threadIdx.x & 31) << 2;   // channel base
    const int rl = threadIdx.x >> 5;          // row lane 0..7
    const int per = (N + gridDim.x - 1) / gridDim.x;
    const int n0 = blockIdx.x * per, n1 = min(N, n0 + per);
    float4 s = make_float4(0.f, 0.f, 0.f, 0.f);
    float4 m = make_float4(-INFINITY, -INFINITY, -INFINITY, -INFINITY);
    for (int n = n0 + rl; n < n1; n += 8) {
        float4 v = *(const float4*)(x + (size_t)n * HID + c4);
        s.x += v.x; s.y += v.y; s.z += v.z; s.w += v.w;
        m.x = fmaxf(m.x, v.x); m.y = fmaxf(m.y, v.y);
        m.z = fmaxf(m.z, v.z); m.w = fmaxf(m.w, v.w);
    }
    *(float4*)&ls[rl][c4] = s;
    *(float4*)&lm[rl][c4] = m;
    __syncthreads();
    if (rl < 4) {
        float4 a = *(float4*)&ls[rl][c4], bq = *(float4*)&ls[rl + 4][c4];
        a.x += bq.x; a.y += bq.y; a.z += bq.z; a.w += bq.w;
        *(float4*)&ls[rl][c4] = a;
        float4 am = *(float4*)&lm[rl][c4], bm = *(float4*)&lm[rl + 4][c4];
        am.x = fmaxf(am.x, bm.x); am.y = fmaxf(am.y, bm.y);
        am.z = fmaxf(am.z, bm.z); am.w = fmaxf(am.w, bm.w);
        *(float4*)&lm[rl][c4] = am;
    }
    __syncthreads();
    if (rl < 2) {
        float4 a = *(float4*)&ls[rl][c4], bq = *(float4*)&ls[rl + 2][c4];
        a.x += bq.x; a.y += bq.y; a.z += bq.z; a.w += bq.w;
        *(float4*)&ls[rl][c4] = a;
        float4 am = *(float4*)&lm[rl][c4], bm = *(float4*)&lm[rl + 2][c4];
        am.x = fmaxf(am.x, bm.x); am.y = fmaxf(am.y, bm.y);
        am.z = fmaxf(am.z, bm.z); am.w = fmaxf(am.w, bm.w);
        *(float4*)&lm[rl][c4] = am;
    }
    __syncthreads();
    if (rl == 0) {
        float4 a = *(float4*)&ls[0][c4], bq = *(float4*)&ls[1][c4];
        a.x += bq.x; a.y += bq.y; a.z += bq.z; a.w += bq.w;
        *(float4*)(psum + (size_t)blockIdx.x * HID + c4) = a;
        float4 am = *(float4*)&lm[0][c4], bm = *(float4*)&lm[1][c4];
        am.x = fmaxf(am.x, bm.x); am.y = fmaxf(am.y, bm.y);
        am.z = fmaxf(am.z, bm.z); am.w = fmaxf(am.w, bm.w);
        *(float4*)(pmax + (size_t)blockIdx.x * HID + c4) = am;
    }
}

__global__ __launch_bounds__(1024) void k_reduce2(const float* __restrict__ psum, const float* __restrict__ pmax,
                                                  int nb, float* __restrict__ out, float invN) {
    __shared__ float ss[8][HID];
    __shared__ float sm[8][HID];
    int h = threadIdx.x & 127;
    int c = threadIdx.x >> 7;          // chunk 0..7
    int per = nb >> 3;
    float s = 0.f, m = -INFINITY;
    for (int b = c * per; b < (c + 1) * per; b++) {
        s += psum[b * HID + h];
        m = fmaxf(m, pmax[b * HID + h]);
    }
    ss[c][h] = s; sm[c][h] = m;
    __syncthreads();
    if (c < 4) { ss[c][h] += ss[c + 4][h]; sm[c][h] = fmaxf(sm[c][h], sm[c + 4][h]); }
    __syncthreads();
    if (c < 2) { ss[c][h] += ss[c + 2][h]; sm[c][h] = fmaxf(sm[c][h], sm[c + 2][h]); }
    __syncthreads();
    if (c == 0) {
        out[h] = (ss[0][h] + ss[1][h]) * invN;
        out[HID + h] = fmaxf(sm[0][h], sm[1][h]);
    }
}

// ---------------- Launch ----------------

extern "C" void kernel_launch(void* const* d_in, const int* in_sizes, int n_in,
                              void* d_out, int out_size, void* d_ws, size_t ws_size,
                              hipStream_t stream) {
    const float* nf    = (const float*)d_in[0];
    const int*   ei    = (const int*)d_in[1];
    const float* W_emb = (const float*)d_in[3];
    const float* b_emb = (const float*)d_in[4];
    const float* Wl    = (const float*)d_in[5];
    const float* bl    = (const float*)d_in[6];
    const float* Wr    = (const float*)d_in[7];
    const float* br    = (const float*)d_in[8];
    const float* att   = (const float*)d_in[9];
    const float* bias  = (const float*)d_in[10];

    const int N = in_sizes[0] / 11;
    const int E = in_sizes[1] / 2;
    const int* src = ei;
    const int* dst = ei + E;

    float* out  = (float*)d_out;
    float* xout = out + 2 * HID;

    // workspace carve-up
    char* w = (char*)d_ws;
    _Float16* xlh  = (_Float16*)w; w += (size_t)N * HID * 2;
    _Float16* xrh  = (_Float16*)w; w += (size_t)N * HID * 2;
    _Float16* xA   = (_Float16*)w; w += (size_t)N * HID * 2;
    _Float16* xB   = (_Float16*)w; w += (size_t)N * HID * 2;
    _Float16* WfL  = (_Float16*)w; w += (size_t)4 * HID * HID * 2;
    _Float16* WfR  = (_Float16*)w; w += (size_t)4 * HID * HID * 2;
    int*   gcnt    = (int*)w;   w += (size_t)256 * 4;
    int*   rowptr  = (int*)w;   w += (size_t)(N + 1) * 4;
    int*   arena   = (int*)w;   w += (size_t)256 * BCAP * 4;
    int*   csr_off = (int*)w;   w += (size_t)E * 4;
    float* psum    = (float*)w; w += (size_t)R1B * HID * 4;
    float* pmax    = (float*)w; w += (size_t)R1B * HID * 4;

    const int nbk = (N + 255) >> 8;       // 196 buckets
    const int nW = 4 * HID * HID;

    // weight fp16 conversion (both matrices) + gcnt zeroing, one launch
    dim3 tg((nW / 4 + 255) / 256, 2);
    k_tof16<<<tg, 256, 0, stream>>>(Wl, Wr, WfL, WfR, gcnt, nW);

    // CSR build (binned two-phase; binB self-scans bucket prefix)
    k_binA<<<(E + ACHUNK - 1) / ACHUNK, 256, 0, stream>>>(src, dst, E, gcnt, arena);
    k_binB<<<nbk, 256, 0, stream>>>(arena, gcnt, N, E, rowptr, csr_off);

    // embedding -> fp16 x (buffer A)
    k_embed<<<(N + 1) / 2, 256, 0, stream>>>(nf, W_emb, b_emb, xA, N);

    dim3 lgrid((N + 255) / 256, 2);
    for (int i = 0; i < 4; i++) {
        // ping-pong: even layers read A write B, odd layers read B write A
        const _Float16* xin = (i & 1) ? xB : xA;
        _Float16* xo        = (i & 1) ? xA : xB;
        k_linear_mfma<<<lgrid, 512, 0, stream>>>(xin,
                                                 WfL + (size_t)i * HID * HID, WfR + (size_t)i * HID * HID,
                                                 bl + i * HID, br + i * HID, xlh, xrh, N);
        k_attn<<<(N + 3) / 4, 256, 0, stream>>>(xlh, xrh, rowptr, csr_off,
                                                att + i * HEADS * 32, bias + i * HID,
                                                xin, xo, xout,
                                                i > 0 ? 1 : 0, i < 3 ? 1 : 0, N);
    }

    k_reduce1<<<R1B, 256, 0, stream>>>(xout, N, psum, pmax);
    k_reduce2<<<1, 1024, 0, stream>>>(psum, pmax, R1B, out, 1.0f / N);
}

// Round 7
// 362.818 us; speedup vs baseline: 1.0956x; 1.0307x over previous
//
#include <hip/hip_runtime.h>
#include <math.h>

#define HID 128
#define HEADS 4
#define NEG_SLOPE 0.2f
#define R1B 512    // reduce1 grid
#define BCAP 8192  // per-bucket arena capacity (mean 4096, +64 sigma)
#define PB 6144    // binB LDS staging ints
#define ACHUNK 4096

typedef float f32x4 __attribute__((ext_vector_type(4)));
typedef _Float16 f16x8 __attribute__((ext_vector_type(8)));
typedef _Float16 f16x4 __attribute__((ext_vector_type(4)));
typedef _Float16 f16x2 __attribute__((ext_vector_type(2)));

#if defined(__has_builtin)
#if __has_builtin(__builtin_amdgcn_fdot2)
#define HAVE_FDOT2 1
#endif
#endif

// ---------------- CSR build: two-phase binned counting sort ----------------

// Phase A: bin 4096 edges/block into bucket arenas. Record = (src<<8)|(dst&255).
__global__ __launch_bounds__(256) void k_binA(const int* __restrict__ src, const int* __restrict__ dst,
                                              int E, int* __restrict__ gcnt, int* __restrict__ arena) {
    __shared__ int lh[256];
    __shared__ int lbase[256];
    __shared__ unsigned short lrank[ACHUNK];
    const int tid = threadIdx.x;
    lh[tid] = 0;
    __syncthreads();
    const int e0 = blockIdx.x * ACHUNK;
    #pragma unroll
    for (int i = 0; i < ACHUNK / 256; i++) {
        int e = e0 + i * 256 + tid;
        if (e < E) {
            int b = dst[e] >> 8;
            lrank[i * 256 + tid] = (unsigned short)atomicAdd(&lh[b], 1);
        }
    }
    __syncthreads();
    if (lh[tid] > 0) lbase[tid] = atomicAdd(&gcnt[tid], lh[tid]);
    __syncthreads();
    #pragma unroll
    for (int i = 0; i < ACHUNK / 256; i++) {
        int e = e0 + i * 256 + tid;
        if (e < E) {
            int d = dst[e];
            int b = d >> 8;
            arena[b * BCAP + lbase[b] + lrank[i * 256 + tid]] = (src[e] << 8) | (d & 255);
        }
    }
}

// Phase B: per bucket -- self-computed bucket prefix, node counts + scan ->
// rowptr; staged, coalesced csr_off dump. csr_off value = src*256.
__global__ __launch_bounds__(256) void k_binB(const int* __restrict__ arena, const int* __restrict__ gcnt,
                                              int N, int E,
                                              int* __restrict__ rowptr, int* __restrict__ csr_off) {
    __shared__ int ncnt[256];
    __shared__ int sbuf[256];
    __shared__ int nstart[256];
    __shared__ int exv[256];
    __shared__ int stage[PB];
    __shared__ unsigned short rk[BCAP];
    const int b = blockIdx.x, tid = threadIdx.x;

    // bucket-prefix scan (gcnt[tid]=0 for tid>=nbk, zeroed by k_prep)
    int gv = gcnt[tid];
    sbuf[tid] = gv;
    __syncthreads();
    for (int off = 1; off < 256; off <<= 1) {
        int t = (tid >= off) ? sbuf[tid - off] : 0;
        __syncthreads();
        sbuf[tid] += t;
        __syncthreads();
    }
    exv[tid] = sbuf[tid] - gv;    // exclusive prefix
    if (b == 0 && tid == 0) rowptr[N] = E;
    __syncthreads();
    const int seg = exv[b];
    const int cnt = gcnt[b];

    ncnt[tid] = 0;
    __syncthreads();
    for (int k = tid; k < cnt; k += 256) {
        int v = arena[b * BCAP + k];
        rk[k] = (unsigned short)atomicAdd(&ncnt[v & 255], 1);
    }
    __syncthreads();
    int c = ncnt[tid];
    sbuf[tid] = c;
    __syncthreads();
    for (int off = 1; off < 256; off <<= 1) {
        int t = (tid >= off) ? sbuf[tid - off] : 0;
        __syncthreads();
        sbuf[tid] += t;
        __syncthreads();
    }
    int myStart = sbuf[tid] - c;   // exclusive
    nstart[tid] = myStart;
    int n = b * 256 + tid;
    if (n < N) rowptr[n] = seg + myStart;
    __syncthreads();
    for (int k = tid; k < cnt; k += 256) {
        int v = arena[b * BCAP + k];
        int pos = nstart[v & 255] + rk[k];
        int val = v & 0xFFFFFF00;
        if (pos < PB) stage[pos] = val;
        else          csr_off[seg + pos] = val;   // statistical overflow guard
    }
    __syncthreads();
    int lim = min(cnt, PB);
    for (int k = tid; k < lim; k += 256) csr_off[seg + k] = stage[k];
}

// ---------------- helpers ----------------

__device__ inline f16x2 absh2(f16x2 v) {
    unsigned u = __builtin_bit_cast(unsigned, v) & 0x7FFF7FFFu;
    return __builtin_bit_cast(f16x2, u);
}

__device__ inline f16x8 zero8() {
    f16x8 z;
    #pragma unroll
    for (int i = 0; i < 8; i++) z[i] = (_Float16)0.f;
    return z;
}

// quad_perm butterfly add via DPP (head groups are hardware quads).
template <int CTRL>
__device__ inline float qp_xor_add(float x) {
    int y = __builtin_amdgcn_update_dpp(0, __builtin_bit_cast(int, x),
                                        CTRL, 0xF, 0xF, true);
    return x + __builtin_bit_cast(float, y);
}

// per-edge logit: leaky_relu(xl+xr) . att  (packed fp16, fdot2 accumulate)
__device__ inline float edge_logit8(f16x8 c,
                                    f16x2 xr0, f16x2 xr1, f16x2 xr2, f16x2 xr3,
                                    f16x2 a0, f16x2 a1, f16x2 a2, f16x2 a3) {
    const f16x2 k06 = (f16x2){(_Float16)0.6f, (_Float16)0.6f};
    const f16x2 k04 = (f16x2){(_Float16)0.4f, (_Float16)0.4f};
    f16x2 c0 = __builtin_shufflevector(c, c, 0, 1);
    f16x2 c1 = __builtin_shufflevector(c, c, 2, 3);
    f16x2 c2 = __builtin_shufflevector(c, c, 4, 5);
    f16x2 c3 = __builtin_shufflevector(c, c, 6, 7);
    f16x2 u0 = c0 + xr0, u1 = c1 + xr1, u2 = c2 + xr2, u3 = c3 + xr3;
    f16x2 l0 = u0 * k06 + absh2(u0) * k04;   // leaky_relu, packed
    f16x2 l1 = u1 * k06 + absh2(u1) * k04;
    f16x2 l2 = u2 * k06 + absh2(u2) * k04;
    f16x2 l3 = u3 * k06 + absh2(u3) * k04;
#ifdef HAVE_FDOT2
    float p = __builtin_amdgcn_fdot2(l0, a0, 0.f, false);
    p = __builtin_amdgcn_fdot2(l1, a1, p, false);
    p = __builtin_amdgcn_fdot2(l2, a2, p, false);
    p = __builtin_amdgcn_fdot2(l3, a3, p, false);
#else
    float p = (float)l0[0] * (float)a0[0] + (float)l0[1] * (float)a0[1]
            + (float)l1[0] * (float)a1[0] + (float)l1[1] * (float)a1[1]
            + (float)l2[0] * (float)a2[0] + (float)l2[1] * (float)a2[1]
            + (float)l3[0] * (float)a3[0] + (float)l3[1] * (float)a3[1];
#endif
    return p;
}

// accumulate one weighted row into acc16[0..3] with LITERAL shuffle indices
#define ACC_ROW(WP, R)                                                        \
    acc16[0] += (WP) * __builtin_shufflevector((R), (R), 0, 1);               \
    acc16[1] += (WP) * __builtin_shufflevector((R), (R), 2, 3);               \
    acc16[2] += (WP) * __builtin_shufflevector((R), (R), 4, 5);               \
    acc16[3] += (WP) * __builtin_shufflevector((R), (R), 6, 7);

// ---------------- Fused prep: embed (blocks < nEmb) + W fp16 convert ----------------
// embed: x = relu(nf @ W_emb.T + b_emb) -> fp16, 2 nodes / 256-thr block.
// convert blocks: 64 per matrix; first convert block zeroes gcnt.

__global__ __launch_bounds__(256) void k_prep(const float* __restrict__ nf, const float* __restrict__ We,
                                              const float* __restrict__ be, _Float16* __restrict__ xh,
                                              int N,
                                              const float* __restrict__ Wl, const float* __restrict__ Wr,
                                              _Float16* __restrict__ WfL, _Float16* __restrict__ WfR,
                                              int* __restrict__ gcnt, int nW) {
    __shared__ float f[2][11];
    const int nEmb = (N + 1) / 2;
    const int bid = blockIdx.x;
    if (bid < nEmb) {
        const int sub = threadIdx.x >> 7;
        const int h   = threadIdx.x & 127;
        const int n   = bid * 2 + sub;
        if (n < N && h < 11) f[sub][h] = nf[(size_t)n * 11 + h];
        __syncthreads();
        if (n >= N) return;
        float acc = be[h];
        #pragma unroll
        for (int k = 0; k < 11; k++) acc += f[sub][k] * We[h * 11 + k];
        xh[(size_t)n * HID + h] = (_Float16)fmaxf(acc, 0.f);
    } else {
        const int tb = bid - nEmb;              // 0..127
        if (tb == 0) gcnt[threadIdx.x] = 0;
        const int mat = tb >> 6;                // 64 blocks per matrix
        const float* x = mat ? Wr : Wl;
        _Float16*    o = mat ? WfR : WfL;
        int base = ((tb & 63) * 256 + threadIdx.x) * 4;
        if (base >= nW) return;
        float4 v = *(const float4*)(x + base);
        f16x4 h = {(_Float16)v.x, (_Float16)v.y, (_Float16)v.z, (_Float16)v.w};
        *(f16x4*)(o + base) = h;
    }
}

// ---------------- MFMA linear, LDS-resident fp16 W, 2 A-tiles/wave ----------------
// Epilogue routed through LDS (node stride 136 halves) -> coalesced 16B stores.

__global__ __launch_bounds__(512) void k_linear_mfma(
        const _Float16* __restrict__ xh,
        const _Float16* __restrict__ WfL, const _Float16* __restrict__ WfR,
        const float* __restrict__ bl, const float* __restrict__ br,
        _Float16* __restrict__ xlh, _Float16* __restrict__ xrh, int N) {
    __shared__ _Float16 lds[17408];   // max(W 16384, transpose 128x136)
    const int t   = threadIdx.x;
    const int mat = blockIdx.y;
    const _Float16* W = mat ? WfR : WfL;

    for (int g = t; g < 2048; g += 512) {
        int r = g >> 4, cc = g & 15;
        int dsto = r * 128 + ((cc ^ (r & 7)) << 3);      // half units
        *(float4*)&lds[dsto] = *(const float4*)(W + g * 8);
    }
    __syncthreads();

    const int wave = t >> 6;
    const int lane = t & 63;
    const int l16  = lane & 15;
    const int quad = lane >> 4;
    const int n0   = blockIdx.x * 256 + wave * 32;

    int arow0 = n0 + l16;
    int arow1 = n0 + 16 + l16;
    if (arow0 >= N) arow0 = N - 1;     // clamp loads; stores guarded below
    if (arow1 >= N) arow1 = N - 1;

    f32x4 acc[2][8];
    #pragma unroll
    for (int u = 0; u < 2; u++)
        #pragma unroll
        for (int s = 0; s < 8; s++) acc[u][s] = (f32x4){0.f, 0.f, 0.f, 0.f};

    #pragma unroll
    for (int k0 = 0; k0 < HID; k0 += 32) {
        f16x8 a0 = *(const f16x8*)(xh + arow0 * HID + k0 + quad * 8);
        f16x8 a1 = *(const f16x8*)(xh + arow1 * HID + k0 + quad * 8);
        const int cc = (k0 >> 3) + quad;
        #pragma unroll
        for (int s = 0; s < 8; s++) {
            const int row = s * 16 + l16;
            const int off = row * 128 + ((cc ^ (l16 & 7)) << 3);
            f16x8 b = *(const f16x8*)&lds[off];
            acc[0][s] = __builtin_amdgcn_mfma_f32_16x16x32_f16(a0, b, acc[0][s], 0, 0, 0);
            acc[1][s] = __builtin_amdgcn_mfma_f32_16x16x32_f16(a1, b, acc[1][s], 0, 0, 0);
        }
    }

    const float* bias = mat ? br : bl;
    _Float16* dst = mat ? xrh : xlh;
    const int wl = wave & 3;            // wave index within a round

    #pragma unroll
    for (int round = 0; round < 2; round++) {
        __syncthreads();                 // W (or previous round) fully consumed
        if ((wave >> 2) == round) {
            #pragma unroll
            for (int s = 0; s < 8; s++) {
                int col = s * 16 + l16;
                float bv = bias[col];
                #pragma unroll
                for (int u = 0; u < 2; u++) {
                    #pragma unroll
                    for (int r = 0; r < 4; r++) {
                        int nd = wl * 32 + u * 16 + quad * 4 + r;   // 0..127
                        lds[nd * 136 + col] = (_Float16)(acc[u][s][r] + bv);
                    }
                }
            }
        }
        __syncthreads();
        // coalesced dump: 128 nodes x 256B = 2048 x 16B units
        const int base_node = blockIdx.x * 256 + round * 128;
        #pragma unroll
        for (int it = 0; it < 4; it++) {
            int idx = it * 512 + t;
            int node = base_node + (idx >> 4);
            if (node < N)
                *(float4*)(dst + (size_t)node * HID + (idx & 15) * 8) =
                    *(float4*)&lds[(idx >> 4) * 136 + (idx & 15) * 8];
        }
    }
}

// ---------------- Fused attention: wave per node, 4 edge streams ----------------
// Round-7: straight-line fast path extended to deg<=24 (~98% of Poisson-16
// nodes): 6 rows/stream issued upfront (max gather MLP, no loop overhead),
// per-pair predication. Slow path (deg>=25, ~2%): depth-2 predicated pipeline.

__global__ __launch_bounds__(256, 8) void k_attn(const _Float16* __restrict__ xlh, const _Float16* __restrict__ xrh,
                                              const int* __restrict__ rowptr, const int* __restrict__ csr_off,
                                              const float* __restrict__ att, const float* __restrict__ bias,
                                              const _Float16* __restrict__ xres, _Float16* __restrict__ outx,
                                              float* __restrict__ out,
                                              int add_res, int want_half, int N) {
    const int wave = threadIdx.x >> 6;
    const int lane = threadIdx.x & 63;
    const int strm = lane >> 4;          // edge stream 0..3
    const int l16  = lane & 15;          // channels [8*l16, 8*l16+8); head = l16>>2
    const int n = blockIdx.x * 4 + wave;
    if (n >= N) return;

    const float4 aA = *(const float4*)(att + 8 * l16);
    const float4 aB = *(const float4*)(att + 8 * l16 + 4);
    const f16x2 a0 = (f16x2){(_Float16)aA.x, (_Float16)aA.y};
    const f16x2 a1 = (f16x2){(_Float16)aA.z, (_Float16)aA.w};
    const f16x2 a2 = (f16x2){(_Float16)aB.x, (_Float16)aB.y};
    const f16x2 a3 = (f16x2){(_Float16)aB.z, (_Float16)aB.w};
    const f16x8 xrv = *(const f16x8*)(xrh + (size_t)n * HID + 8 * l16);
    const f16x2 xr0 = __builtin_shufflevector(xrv, xrv, 0, 1);
    const f16x2 xr1 = __builtin_shufflevector(xrv, xrv, 2, 3);
    const f16x2 xr2 = __builtin_shufflevector(xrv, xrv, 4, 5);
    const f16x2 xr3 = __builtin_shufflevector(xrv, xrv, 6, 7);
    const int s0 = rowptr[n], s1 = rowptr[n + 1];
    const int deg = s1 - s0;

    float den = 0.f;
    f16x2 acc16[4];
    #pragma unroll
    for (int q = 0; q < 4; q++) acc16[q] = (f16x2){(_Float16)0.f, (_Float16)0.f};

    const char* xlb = (const char*)xlh + l16 * 16;  // lane's 16B slice within a row
    const int j = s0 + 2 * strm;                    // stream's first edge

    if (deg > 0 && deg <= 24) {
        // ---- fast path: stream covers pairs {j,j+1},{j+8,j+9},{j+16,j+17} ----
        const int last = s1 - 1;
        f16x8 r0, r1, r2, r3, r4, r5;
        if (j < s1) {
            int o0 = csr_off[j];
            int o1 = csr_off[min(j + 1, last)];
            r0 = *(const f16x8*)(xlb + o0);
            r1 = *(const f16x8*)(xlb + o1);
        } else { r0 = zero8(); r1 = zero8(); }
        if (j + 8 < s1) {
            int o2 = csr_off[j + 8];
            int o3 = csr_off[min(j + 9, last)];
            r2 = *(const f16x8*)(xlb + o2);
            r3 = *(const f16x8*)(xlb + o3);
        } else { r2 = zero8(); r3 = zero8(); }
        if (j + 16 < s1) {
            int o4 = csr_off[j + 16];
            int o5 = csr_off[min(j + 17, last)];
            r4 = *(const f16x8*)(xlb + o4);
            r5 = *(const f16x8*)(xlb + o5);
        } else { r4 = zero8(); r5 = zero8(); }

        float p0 = edge_logit8(r0, xr0, xr1, xr2, xr3, a0, a1, a2, a3);
        float p1 = edge_logit8(r1, xr0, xr1, xr2, xr3, a0, a1, a2, a3);
        float p2 = edge_logit8(r2, xr0, xr1, xr2, xr3, a0, a1, a2, a3);
        float p3 = edge_logit8(r3, xr0, xr1, xr2, xr3, a0, a1, a2, a3);
        float p4 = edge_logit8(r4, xr0, xr1, xr2, xr3, a0, a1, a2, a3);
        float p5 = edge_logit8(r5, xr0, xr1, xr2, xr3, a0, a1, a2, a3);
        p0 = qp_xor_add<0xB1>(p0); p0 = qp_xor_add<0x4E>(p0);
        p1 = qp_xor_add<0xB1>(p1); p1 = qp_xor_add<0x4E>(p1);
        p2 = qp_xor_add<0xB1>(p2); p2 = qp_xor_add<0x4E>(p2);
        p3 = qp_xor_add<0xB1>(p3); p3 = qp_xor_add<0x4E>(p3);
        p4 = qp_xor_add<0xB1>(p4); p4 = qp_xor_add<0x4E>(p4);
        p5 = qp_xor_add<0xB1>(p5); p5 = qp_xor_add<0x4E>(p5);
        float w0 = (j      < s1) ? __expf(p0) : 0.f;
        float w1 = (j + 1  < s1) ? __expf(p1) : 0.f;
        float w2 = (j + 8  < s1) ? __expf(p2) : 0.f;
        float w3 = (j + 9  < s1) ? __expf(p3) : 0.f;
        float w4 = (j + 16 < s1) ? __expf(p4) : 0.f;
        float w5 = (j + 17 < s1) ? __expf(p5) : 0.f;
        den += (w0 + w1) + (w2 + w3) + (w4 + w5);
        f16x2 wp0 = (f16x2){(_Float16)w0, (_Float16)w0};
        f16x2 wp1 = (f16x2){(_Float16)w1, (_Float16)w1};
        f16x2 wp2 = (f16x2){(_Float16)w2, (_Float16)w2};
        f16x2 wp3 = (f16x2){(_Float16)w3, (_Float16)w3};
        f16x2 wp4 = (f16x2){(_Float16)w4, (_Float16)w4};
        f16x2 wp5 = (f16x2){(_Float16)w5, (_Float16)w5};
        ACC_ROW(wp0, r0)
        ACC_ROW(wp1, r1)
        ACC_ROW(wp2, r2)
        ACC_ROW(wp3, r3)
        ACC_ROW(wp4, r4)
        ACC_ROW(wp5, r5)
    } else if (deg > 24) {
        // ---- slow path: depth-2 pipeline, predicated prefetch ----
        const int last = s1 - 1;
        int jj = j;
        // prologue: all 4 rows valid (deg>=25 => jj+9 <= s0+15 < s1)
        f16x8 pa0 = *(const f16x8*)(xlb + csr_off[jj]);
        f16x8 pb0 = *(const f16x8*)(xlb + csr_off[jj + 1]);
        f16x8 pa1 = *(const f16x8*)(xlb + csr_off[jj + 8]);
        f16x8 pb1 = *(const f16x8*)(xlb + csr_off[jj + 9]);
        int oa = csr_off[min(jj + 16, last)];
        int ob = csr_off[min(jj + 17, last)];
        while (jj < s1) {
            f16x8 ca = pa0, cb = pb0;
            pa0 = pa1; pb0 = pb1;
            if (jj + 16 < s1) {          // predicated prefetch: no dup gathers
                pa1 = *(const f16x8*)(xlb + oa);
                pb1 = *(const f16x8*)(xlb + ob);
                oa = csr_off[min(jj + 24, last)];
                ob = csr_off[min(jj + 25, last)];
            } else { pa1 = zero8(); pb1 = zero8(); }

            float pa = edge_logit8(ca, xr0, xr1, xr2, xr3, a0, a1, a2, a3);
            float pb = edge_logit8(cb, xr0, xr1, xr2, xr3, a0, a1, a2, a3);
            pa = qp_xor_add<0xB1>(pa); pa = qp_xor_add<0x4E>(pa);
            pb = qp_xor_add<0xB1>(pb); pb = qp_xor_add<0x4E>(pb);
            float wa = __expf(pa);
            float wb = (jj + 1 < s1) ? __expf(pb) : 0.f;
            den += wa + wb;
            f16x2 wpa = (f16x2){(_Float16)wa, (_Float16)wa};
            f16x2 wpb = (f16x2){(_Float16)wb, (_Float16)wb};
            ACC_ROW(wpa, ca)
            ACC_ROW(wpb, cb)
            jj += 8;
        }
    }

    // merge the four streams (lane stride 16/32) on packed f16x2
    den += __shfl_xor(den, 16);
    den += __shfl_xor(den, 32);
    #pragma unroll
    for (int q = 0; q < 4; q++) {
        float pk = __builtin_bit_cast(float, acc16[q]);
        acc16[q] += __builtin_bit_cast(f16x2, __shfl_xor(pk, 16));
        pk = __builtin_bit_cast(float, acc16[q]);
        acc16[q] += __builtin_bit_cast(f16x2, __shfl_xor(pk, 32));
    }

    if (strm == 0) {
        float acc[8];
        #pragma unroll
        for (int q = 0; q < 4; q++) {
            acc[2 * q]     = (float)acc16[q][0];
            acc[2 * q + 1] = (float)acc16[q][1];
        }
        float4 bA = *(const float4*)(bias + 8 * l16);
        float4 bB = *(const float4*)(bias + 8 * l16 + 4);
        float b[8] = {bA.x, bA.y, bA.z, bA.w, bB.x, bB.y, bB.z, bB.w};
        float inv = (den > 0.f) ? 1.f / den : 0.f;
        float v[8];
        #pragma unroll
        for (int q = 0; q < 8; q++) v[q] = fmaxf(acc[q] * inv + b[q], 0.f);
        if (add_res) {
            f16x8 r = *(const f16x8*)(xres + (size_t)n * HID + 8 * l16);
            #pragma unroll
            for (int q = 0; q < 8; q++) v[q] += (float)r[q];
        }
        if (want_half) {
            f16x8 h;
            #pragma unroll
            for (int q = 0; q < 8; q++) h[q] = (_Float16)v[q];
            *(f16x8*)(outx + (size_t)n * HID + 8 * l16) = h;
        } else {
            *(float4*)(out + (size_t)n * HID + 8 * l16)     = make_float4(v[0], v[1], v[2], v[3]);
            *(float4*)(out + (size_t)n * HID + 8 * l16 + 4) = make_float4(v[4], v[5], v[6], v[7]);
        }
    }
}

// ---------------- Graph readout: mean + max over nodes ----------------

__global__ __launch_bounds__(256) void k_reduce1(const float* __restrict__ x, int N,
                                                 float* __restrict__ psum, float* __restrict__ pmax) {
    __shared__ float ls[8][HID];
    __shared__ float lm[8][HID];
    const int c4 = (threadIdx.x & 31) << 2;   // channel base
    const int rl = threadIdx.x >> 5;          // row lane 0..7
    const int per = (N + gridDim.x - 1) / gridDim.x;
    const int n0 = blockIdx.x * per, n1 = min(N, n0 + per);
    float4 s = make_float4(0.f, 0.f, 0.f, 0.f);
    float4 m = make_float4(-INFINITY, -INFINITY, -INFINITY, -INFINITY);
    for (int n = n0 + rl; n < n1; n += 8) {
        float4 v = *(const float4*)(x + (size_t)n * HID + c4);
        s.x += v.x; s.y += v.y; s.z += v.z; s.w += v.w;
        m.x = fmaxf(m.x, v.x); m.y = fmaxf(m.y, v.y);
        m.z = fmaxf(m.z, v.z); m.w = fmaxf(m.w, v.w);
    }
    *(float4*)&ls[rl][c4] = s;
    *(float4*)&lm[rl][c4] = m;
    __syncthreads();
    if (rl < 4) {
        float4 a = *(float4*)&ls[rl][c4], bq = *(float4*)&ls[rl + 4][c4];
        a.x += bq.x; a.y += bq.y; a.z += bq.z; a.w += bq.w;
        *(float4*)&ls[rl][c4] = a;
        float4 am = *(float4*)&lm[rl][c4], bm = *(float4*)&lm[rl + 4][c4];
        am.x = fmaxf(am.x, bm.x); am.y = fmaxf(am.y, bm.y);
        am.z = fmaxf(am.z, bm.z); am.w = fmaxf(am.w, bm.w);
        *(float4*)&lm[rl][c4] = am;
    }
    __syncthreads();
    if (rl < 2) {
        float4 a = *(float4*)&ls[rl][c4], bq = *(float4*)&ls[rl + 2][c4];
        a.x += bq.x; a.y += bq.y; a.z += bq.z; a.w += bq.w;
        *(float4*)&ls[rl][c4] = a;
        float4 am = *(float4*)&lm[rl][c4], bm = *(float4*)&lm[rl + 2][c4];
        am.x = fmaxf(am.x, bm.x); am.y = fmaxf(am.y, bm.y);
        am.z = fmaxf(am.z, bm.z); am.w = fmaxf(am.w, bm.w);
        *(float4*)&lm[rl][c4] = am;
    }
    __syncthreads();
    if (rl == 0) {
        float4 a = *(float4*)&ls[0][c4], bq = *(float4*)&ls[1][c4];
        a.x += bq.x; a.y += bq.y; a.z += bq.z; a.w += bq.w;
        *(float4*)(psum + (size_t)blockIdx.x * HID + c4) = a;
        float4 am = *(float4*)&lm[0][c4], bm = *(float4*)&lm[1][c4];
        am.x = fmaxf(am.x, bm.x); am.y = fmaxf(am.y, bm.y);
        am.z = fmaxf(am.z, bm.z); am.w = fmaxf(am.w, bm.w);
        *(float4*)(pmax + (size_t)blockIdx.x * HID + c4) = am;
    }
}

__global__ __launch_bounds__(1024) void k_reduce2(const float* __restrict__ psum, const float* __restrict__ pmax,
                                                  int nb, float* __restrict__ out, float invN) {
    __shared__ float ss[8][HID];
    __shared__ float sm[8][HID];
    int h = threadIdx.x & 127;
    int c = threadIdx.x >> 7;          // chunk 0..7
    int per = nb >> 3;
    float s = 0.f, m = -INFINITY;
    for (int b = c * per; b < (c + 1) * per; b++) {
        s += psum[b * HID + h];
        m = fmaxf(m, pmax[b * HID + h]);
    }
    ss[c][h] = s; sm[c][h] = m;
    __syncthreads();
    if (c < 4) { ss[c][h] += ss[c + 4][h]; sm[c][h] = fmaxf(sm[c][h], sm[c + 4][h]); }
    __syncthreads();
    if (c < 2) { ss[c][h] += ss[c + 2][h]; sm[c][h] = fmaxf(sm[c][h], sm[c + 2][h]); }
    __syncthreads();
    if (c == 0) {
        out[h] = (ss[0][h] + ss[1][h]) * invN;
        out[HID + h] = fmaxf(sm[0][h], sm[1][h]);
    }
}

// ---------------- Launch ----------------

extern "C" void kernel_launch(void* const* d_in, const int* in_sizes, int n_in,
                              void* d_out, int out_size, void* d_ws, size_t ws_size,
                              hipStream_t stream) {
    const float* nf    = (const float*)d_in[0];
    const int*   ei    = (const int*)d_in[1];
    const float* W_emb = (const float*)d_in[3];
    const float* b_emb = (const float*)d_in[4];
    const float* Wl    = (const float*)d_in[5];
    const float* bl    = (const float*)d_in[6];
    const float* Wr    = (const float*)d_in[7];
    const float* br    = (const float*)d_in[8];
    const float* att   = (const float*)d_in[9];
    const float* bias  = (const float*)d_in[10];

    const int N = in_sizes[0] / 11;
    const int E = in_sizes[1] / 2;
    const int* src = ei;
    const int* dst = ei + E;

    float* out  = (float*)d_out;
    float* xout = out + 2 * HID;

    // workspace carve-up
    char* w = (char*)d_ws;
    _Float16* xlh  = (_Float16*)w; w += (size_t)N * HID * 2;
    _Float16* xrh  = (_Float16*)w; w += (size_t)N * HID * 2;
    _Float16* xA   = (_Float16*)w; w += (size_t)N * HID * 2;
    _Float16* xB   = (_Float16*)w; w += (size_t)N * HID * 2;
    _Float16* WfL  = (_Float16*)w; w += (size_t)4 * HID * HID * 2;
    _Float16* WfR  = (_Float16*)w; w += (size_t)4 * HID * HID * 2;
    int*   gcnt    = (int*)w;   w += (size_t)256 * 4;
    int*   rowptr  = (int*)w;   w += (size_t)(N + 1) * 4;
    int*   arena   = (int*)w;   w += (size_t)256 * BCAP * 4;
    int*   csr_off = (int*)w;   w += (size_t)E * 4;
    float* psum    = (float*)w; w += (size_t)R1B * HID * 4;
    float* pmax    = (float*)w; w += (size_t)R1B * HID * 4;

    const int nbk = (N + 255) >> 8;       // 196 buckets
    const int nW = 4 * HID * HID;

    // fused: embedding + weight fp16 conversion + gcnt zeroing
    const int nEmb = (N + 1) / 2;
    k_prep<<<nEmb + 128, 256, 0, stream>>>(nf, W_emb, b_emb, xA, N,
                                           Wl, Wr, WfL, WfR, gcnt, nW);

    // CSR build (binned two-phase; binB self-scans bucket prefix)
    k_binA<<<(E + ACHUNK - 1) / ACHUNK, 256, 0, stream>>>(src, dst, E, gcnt, arena);
    k_binB<<<nbk, 256, 0, stream>>>(arena, gcnt, N, E, rowptr, csr_off);

    dim3 lgrid((N + 255) / 256, 2);
    for (int i = 0; i < 4; i++) {
        // ping-pong: even layers read A write B, odd layers read B write A
        const _Float16* xin = (i & 1) ? xB : xA;
        _Float16* xo        = (i & 1) ? xA : xB;
        k_linear_mfma<<<lgrid, 512, 0, stream>>>(xin,
                                                 WfL + (size_t)i * HID * HID, WfR + (size_t)i * HID * HID,
                                                 bl + i * HID, br + i * HID, xlh, xrh, N);
        k_attn<<<(N + 3) / 4, 256, 0, stream>>>(xlh, xrh, rowptr, csr_off,
                                                att + i * HEADS * 32, bias + i * HID,
                                                xin, xo, xout,
                                                i > 0 ? 1 : 0, i < 3 ? 1 : 0, N);
    }

    k_reduce1<<<R1B, 256, 0, stream>>>(xout, N, psum, pmax);
    k_reduce2<<<1, 1024, 0, stream>>>(psum, pmax, R1B, out, 1.0f / N);
}

// Round 8
// 354.227 us; speedup vs baseline: 1.1222x; 1.0243x over previous
//
#include <hip/hip_runtime.h>
#include <math.h>

#define HID 128
#define HEADS 4
#define NEG_SLOPE 0.2f
#define R1B 512    // reduce1 grid
#define BCAP 8192  // per-bucket arena capacity (mean 4096, +64 sigma)
#define PB 6144    // binB LDS staging ints
#define ACHUNK 4096

typedef float f32x4 __attribute__((ext_vector_type(4)));
typedef _Float16 f16x8 __attribute__((ext_vector_type(8)));
typedef _Float16 f16x4 __attribute__((ext_vector_type(4)));
typedef _Float16 f16x2 __attribute__((ext_vector_type(2)));

#if defined(__has_builtin)
#if __has_builtin(__builtin_amdgcn_fdot2)
#define HAVE_FDOT2 1
#endif
#endif

// ---------------- CSR build: two-phase binned counting sort ----------------

// Phase A: bin 4096 edges/block into bucket arenas. Record = (src<<8)|(dst&255).
__global__ __launch_bounds__(256) void k_binA(const int* __restrict__ src, const int* __restrict__ dst,
                                              int E, int* __restrict__ gcnt, int* __restrict__ arena) {
    __shared__ int lh[256];
    __shared__ int lbase[256];
    __shared__ unsigned short lrank[ACHUNK];
    const int tid = threadIdx.x;
    lh[tid] = 0;
    __syncthreads();
    const int e0 = blockIdx.x * ACHUNK;
    #pragma unroll
    for (int i = 0; i < ACHUNK / 256; i++) {
        int e = e0 + i * 256 + tid;
        if (e < E) {
            int b = dst[e] >> 8;
            lrank[i * 256 + tid] = (unsigned short)atomicAdd(&lh[b], 1);
        }
    }
    __syncthreads();
    if (lh[tid] > 0) lbase[tid] = atomicAdd(&gcnt[tid], lh[tid]);
    __syncthreads();
    #pragma unroll
    for (int i = 0; i < ACHUNK / 256; i++) {
        int e = e0 + i * 256 + tid;
        if (e < E) {
            int d = dst[e];
            int b = d >> 8;
            arena[b * BCAP + lbase[b] + lrank[i * 256 + tid]] = (src[e] << 8) | (d & 255);
        }
    }
}

// Phase B: per bucket -- self-computed bucket prefix, node counts + scan ->
// rowptr; staged, coalesced csr_off dump. csr_off value = src*256.
__global__ __launch_bounds__(256) void k_binB(const int* __restrict__ arena, const int* __restrict__ gcnt,
                                              int N, int E,
                                              int* __restrict__ rowptr, int* __restrict__ csr_off) {
    __shared__ int ncnt[256];
    __shared__ int sbuf[256];
    __shared__ int nstart[256];
    __shared__ int exv[256];
    __shared__ int stage[PB];
    __shared__ unsigned short rk[BCAP];
    const int b = blockIdx.x, tid = threadIdx.x;

    // bucket-prefix scan (gcnt[tid]=0 for tid>=nbk, zeroed by k_prep)
    int gv = gcnt[tid];
    sbuf[tid] = gv;
    __syncthreads();
    for (int off = 1; off < 256; off <<= 1) {
        int t = (tid >= off) ? sbuf[tid - off] : 0;
        __syncthreads();
        sbuf[tid] += t;
        __syncthreads();
    }
    exv[tid] = sbuf[tid] - gv;    // exclusive prefix
    if (b == 0 && tid == 0) rowptr[N] = E;
    __syncthreads();
    const int seg = exv[b];
    const int cnt = gcnt[b];

    ncnt[tid] = 0;
    __syncthreads();
    for (int k = tid; k < cnt; k += 256) {
        int v = arena[b * BCAP + k];
        rk[k] = (unsigned short)atomicAdd(&ncnt[v & 255], 1);
    }
    __syncthreads();
    int c = ncnt[tid];
    sbuf[tid] = c;
    __syncthreads();
    for (int off = 1; off < 256; off <<= 1) {
        int t = (tid >= off) ? sbuf[tid - off] : 0;
        __syncthreads();
        sbuf[tid] += t;
        __syncthreads();
    }
    int myStart = sbuf[tid] - c;   // exclusive
    nstart[tid] = myStart;
    int n = b * 256 + tid;
    if (n < N) rowptr[n] = seg + myStart;
    __syncthreads();
    for (int k = tid; k < cnt; k += 256) {
        int v = arena[b * BCAP + k];
        int pos = nstart[v & 255] + rk[k];
        int val = v & 0xFFFFFF00;
        if (pos < PB) stage[pos] = val;
        else          csr_off[seg + pos] = val;   // statistical overflow guard
    }
    __syncthreads();
    int lim = min(cnt, PB);
    for (int k = tid; k < lim; k += 256) csr_off[seg + k] = stage[k];
}

// ---------------- helpers ----------------

__device__ inline f16x2 absh2(f16x2 v) {
    unsigned u = __builtin_bit_cast(unsigned, v) & 0x7FFF7FFFu;
    return __builtin_bit_cast(f16x2, u);
}

__device__ inline f16x8 zero8() {
    f16x8 z;
    #pragma unroll
    for (int i = 0; i < 8; i++) z[i] = (_Float16)0.f;
    return z;
}

// quad_perm butterfly add via DPP (head groups are hardware quads).
template <int CTRL>
__device__ inline float qp_xor_add(float x) {
    int y = __builtin_amdgcn_update_dpp(0, __builtin_bit_cast(int, x),
                                        CTRL, 0xF, 0xF, true);
    return x + __builtin_bit_cast(float, y);
}

// per-edge logit: leaky_relu(xl+xr) . att  (packed fp16, fdot2 accumulate)
__device__ inline float edge_logit8(f16x8 c,
                                    f16x2 xr0, f16x2 xr1, f16x2 xr2, f16x2 xr3,
                                    f16x2 a0, f16x2 a1, f16x2 a2, f16x2 a3) {
    const f16x2 k06 = (f16x2){(_Float16)0.6f, (_Float16)0.6f};
    const f16x2 k04 = (f16x2){(_Float16)0.4f, (_Float16)0.4f};
    f16x2 c0 = __builtin_shufflevector(c, c, 0, 1);
    f16x2 c1 = __builtin_shufflevector(c, c, 2, 3);
    f16x2 c2 = __builtin_shufflevector(c, c, 4, 5);
    f16x2 c3 = __builtin_shufflevector(c, c, 6, 7);
    f16x2 u0 = c0 + xr0, u1 = c1 + xr1, u2 = c2 + xr2, u3 = c3 + xr3;
    f16x2 l0 = u0 * k06 + absh2(u0) * k04;   // leaky_relu, packed
    f16x2 l1 = u1 * k06 + absh2(u1) * k04;
    f16x2 l2 = u2 * k06 + absh2(u2) * k04;
    f16x2 l3 = u3 * k06 + absh2(u3) * k04;
#ifdef HAVE_FDOT2
    float p = __builtin_amdgcn_fdot2(l0, a0, 0.f, false);
    p = __builtin_amdgcn_fdot2(l1, a1, p, false);
    p = __builtin_amdgcn_fdot2(l2, a2, p, false);
    p = __builtin_amdgcn_fdot2(l3, a3, p, false);
#else
    float p = (float)l0[0] * (float)a0[0] + (float)l0[1] * (float)a0[1]
            + (float)l1[0] * (float)a1[0] + (float)l1[1] * (float)a1[1]
            + (float)l2[0] * (float)a2[0] + (float)l2[1] * (float)a2[1]
            + (float)l3[0] * (float)a3[0] + (float)l3[1] * (float)a3[1];
#endif
    return p;
}

// accumulate one weighted row into acc16[0..3] with LITERAL shuffle indices
#define ACC_ROW(WP, R)                                                        \
    acc16[0] += (WP) * __builtin_shufflevector((R), (R), 0, 1);               \
    acc16[1] += (WP) * __builtin_shufflevector((R), (R), 2, 3);               \
    acc16[2] += (WP) * __builtin_shufflevector((R), (R), 4, 5);               \
    acc16[3] += (WP) * __builtin_shufflevector((R), (R), 6, 7);

// ---------------- Fused prep: embed (blocks < nEmb) + W fp16 convert ----------------

__global__ __launch_bounds__(256) void k_prep(const float* __restrict__ nf, const float* __restrict__ We,
                                              const float* __restrict__ be, _Float16* __restrict__ xh,
                                              int N,
                                              const float* __restrict__ Wl, const float* __restrict__ Wr,
                                              _Float16* __restrict__ WfL, _Float16* __restrict__ WfR,
                                              int* __restrict__ gcnt, int nW) {
    __shared__ float f[2][11];
    const int nEmb = (N + 1) / 2;
    const int bid = blockIdx.x;
    if (bid < nEmb) {
        const int sub = threadIdx.x >> 7;
        const int h   = threadIdx.x & 127;
        const int n   = bid * 2 + sub;
        if (n < N && h < 11) f[sub][h] = nf[(size_t)n * 11 + h];
        __syncthreads();
        if (n >= N) return;
        float acc = be[h];
        #pragma unroll
        for (int k = 0; k < 11; k++) acc += f[sub][k] * We[h * 11 + k];
        xh[(size_t)n * HID + h] = (_Float16)fmaxf(acc, 0.f);
    } else {
        const int tb = bid - nEmb;              // 0..127
        if (tb == 0) gcnt[threadIdx.x] = 0;
        const int mat = tb >> 6;                // 64 blocks per matrix
        const float* x = mat ? Wr : Wl;
        _Float16*    o = mat ? WfR : WfL;
        int base = ((tb & 63) * 256 + threadIdx.x) * 4;
        if (base >= nW) return;
        float4 v = *(const float4*)(x + base);
        f16x4 h = {(_Float16)v.x, (_Float16)v.y, (_Float16)v.z, (_Float16)v.w};
        *(f16x4*)(o + base) = h;
    }
}

// ---------------- MFMA linear, LDS-resident fp16 W, 2 A-tiles/wave ----------------
// Epilogue routed through LDS (node stride 136 halves) -> coalesced 16B stores.

__global__ __launch_bounds__(512) void k_linear_mfma(
        const _Float16* __restrict__ xh,
        const _Float16* __restrict__ WfL, const _Float16* __restrict__ WfR,
        const float* __restrict__ bl, const float* __restrict__ br,
        _Float16* __restrict__ xlh, _Float16* __restrict__ xrh, int N) {
    __shared__ _Float16 lds[17408];   // max(W 16384, transpose 128x136)
    const int t   = threadIdx.x;
    const int mat = blockIdx.y;
    const _Float16* W = mat ? WfR : WfL;

    for (int g = t; g < 2048; g += 512) {
        int r = g >> 4, cc = g & 15;
        int dsto = r * 128 + ((cc ^ (r & 7)) << 3);      // half units
        *(float4*)&lds[dsto] = *(const float4*)(W + g * 8);
    }
    __syncthreads();

    const int wave = t >> 6;
    const int lane = t & 63;
    const int l16  = lane & 15;
    const int quad = lane >> 4;
    const int n0   = blockIdx.x * 256 + wave * 32;

    int arow0 = n0 + l16;
    int arow1 = n0 + 16 + l16;
    if (arow0 >= N) arow0 = N - 1;     // clamp loads; stores guarded below
    if (arow1 >= N) arow1 = N - 1;

    f32x4 acc[2][8];
    #pragma unroll
    for (int u = 0; u < 2; u++)
        #pragma unroll
        for (int s = 0; s < 8; s++) acc[u][s] = (f32x4){0.f, 0.f, 0.f, 0.f};

    #pragma unroll
    for (int k0 = 0; k0 < HID; k0 += 32) {
        f16x8 a0 = *(const f16x8*)(xh + arow0 * HID + k0 + quad * 8);
        f16x8 a1 = *(const f16x8*)(xh + arow1 * HID + k0 + quad * 8);
        const int cc = (k0 >> 3) + quad;
        #pragma unroll
        for (int s = 0; s < 8; s++) {
            const int row = s * 16 + l16;
            const int off = row * 128 + ((cc ^ (l16 & 7)) << 3);
            f16x8 b = *(const f16x8*)&lds[off];
            acc[0][s] = __builtin_amdgcn_mfma_f32_16x16x32_f16(a0, b, acc[0][s], 0, 0, 0);
            acc[1][s] = __builtin_amdgcn_mfma_f32_16x16x32_f16(a1, b, acc[1][s], 0, 0, 0);
        }
    }

    const float* bias = mat ? br : bl;
    _Float16* dst = mat ? xrh : xlh;
    const int wl = wave & 3;            // wave index within a round

    #pragma unroll
    for (int round = 0; round < 2; round++) {
        __syncthreads();                 // W (or previous round) fully consumed
        if ((wave >> 2) == round) {
            #pragma unroll
            for (int s = 0; s < 8; s++) {
                int col = s * 16 + l16;
                float bv = bias[col];
                #pragma unroll
                for (int u = 0; u < 2; u++) {
                    #pragma unroll
                    for (int r = 0; r < 4; r++) {
                        int nd = wl * 32 + u * 16 + quad * 4 + r;   // 0..127
                        lds[nd * 136 + col] = (_Float16)(acc[u][s][r] + bv);
                    }
                }
            }
        }
        __syncthreads();
        // coalesced dump: 128 nodes x 256B = 2048 x 16B units
        const int base_node = blockIdx.x * 256 + round * 128;
        #pragma unroll
        for (int it = 0; it < 4; it++) {
            int idx = it * 512 + t;
            int node = base_node + (idx >> 4);
            if (node < N)
                *(float4*)(dst + (size_t)node * HID + (idx & 15) * 8) =
                    *(float4*)&lds[(idx >> 4) * 136 + (idx & 15) * 8];
        }
    }
}

// ---------------- Fused attention: wave per node, 4 edge streams ----------------
// Round-8: 6-pair upfront loads kept (gather MLP), but each pair's COMPUTE is
// guarded by its lane-predicate. For deg<=16 the pair-2 guard is false on all
// 64 lanes -> s_cbranch_execz skips the whole block (zero VALU); same for
// pair-1 when deg<=8. Fixes Round-7's VALUBusy 62% (wasted logits on zeroed
// rows). Slow path (deg>=25, ~2%): depth-2 predicated pipeline.

__global__ __launch_bounds__(256, 8) void k_attn(const _Float16* __restrict__ xlh, const _Float16* __restrict__ xrh,
                                              const int* __restrict__ rowptr, const int* __restrict__ csr_off,
                                              const float* __restrict__ att, const float* __restrict__ bias,
                                              const _Float16* __restrict__ xres, _Float16* __restrict__ outx,
                                              float* __restrict__ out,
                                              int add_res, int want_half, int N) {
    const int wave = threadIdx.x >> 6;
    const int lane = threadIdx.x & 63;
    const int strm = lane >> 4;          // edge stream 0..3
    const int l16  = lane & 15;          // channels [8*l16, 8*l16+8); head = l16>>2
    const int n = blockIdx.x * 4 + wave;
    if (n >= N) return;

    const float4 aA = *(const float4*)(att + 8 * l16);
    const float4 aB = *(const float4*)(att + 8 * l16 + 4);
    const f16x2 a0 = (f16x2){(_Float16)aA.x, (_Float16)aA.y};
    const f16x2 a1 = (f16x2){(_Float16)aA.z, (_Float16)aA.w};
    const f16x2 a2 = (f16x2){(_Float16)aB.x, (_Float16)aB.y};
    const f16x2 a3 = (f16x2){(_Float16)aB.z, (_Float16)aB.w};
    const f16x8 xrv = *(const f16x8*)(xrh + (size_t)n * HID + 8 * l16);
    const f16x2 xr0 = __builtin_shufflevector(xrv, xrv, 0, 1);
    const f16x2 xr1 = __builtin_shufflevector(xrv, xrv, 2, 3);
    const f16x2 xr2 = __builtin_shufflevector(xrv, xrv, 4, 5);
    const f16x2 xr3 = __builtin_shufflevector(xrv, xrv, 6, 7);
    const int s0 = rowptr[n], s1 = rowptr[n + 1];
    const int deg = s1 - s0;

    float den = 0.f;
    f16x2 acc16[4];
    #pragma unroll
    for (int q = 0; q < 4; q++) acc16[q] = (f16x2){(_Float16)0.f, (_Float16)0.f};

    const char* xlb = (const char*)xlh + l16 * 16;  // lane's 16B slice within a row
    const int j = s0 + 2 * strm;                    // stream's first edge

    if (deg > 0 && deg <= 24) {
        // ---- fast path: loads upfront, compute per-pair exec-guarded ----
        const int last = s1 - 1;
        f16x8 r0 = zero8(), r1 = zero8(), r2 = zero8(),
              r3 = zero8(), r4 = zero8(), r5 = zero8();
        if (j < s1) {
            int o0 = csr_off[j];
            int o1 = csr_off[min(j + 1, last)];
            r0 = *(const f16x8*)(xlb + o0);
            r1 = *(const f16x8*)(xlb + o1);
        }
        if (j + 8 < s1) {
            int o2 = csr_off[j + 8];
            int o3 = csr_off[min(j + 9, last)];
            r2 = *(const f16x8*)(xlb + o2);
            r3 = *(const f16x8*)(xlb + o3);
        }
        if (j + 16 < s1) {
            int o4 = csr_off[j + 16];
            int o5 = csr_off[min(j + 17, last)];
            r4 = *(const f16x8*)(xlb + o4);
            r5 = *(const f16x8*)(xlb + o5);
        }

        if (j < s1) {       // pair 0 (execz-skips only for tiny tails)
            float p0 = edge_logit8(r0, xr0, xr1, xr2, xr3, a0, a1, a2, a3);
            float p1 = edge_logit8(r1, xr0, xr1, xr2, xr3, a0, a1, a2, a3);
            p0 = qp_xor_add<0xB1>(p0); p0 = qp_xor_add<0x4E>(p0);
            p1 = qp_xor_add<0xB1>(p1); p1 = qp_xor_add<0x4E>(p1);
            float w0 = __expf(p0);
            float w1 = (j + 1 < s1) ? __expf(p1) : 0.f;
            den += w0 + w1;
            f16x2 wp0 = (f16x2){(_Float16)w0, (_Float16)w0};
            f16x2 wp1 = (f16x2){(_Float16)w1, (_Float16)w1};
            ACC_ROW(wp0, r0)
            ACC_ROW(wp1, r1)
        }
        if (j + 8 < s1) {   // pair 1 (execz-skips whole wave when deg<=8)
            float p2 = edge_logit8(r2, xr0, xr1, xr2, xr3, a0, a1, a2, a3);
            float p3 = edge_logit8(r3, xr0, xr1, xr2, xr3, a0, a1, a2, a3);
            p2 = qp_xor_add<0xB1>(p2); p2 = qp_xor_add<0x4E>(p2);
            p3 = qp_xor_add<0xB1>(p3); p3 = qp_xor_add<0x4E>(p3);
            float w2 = __expf(p2);
            float w3 = (j + 9 < s1) ? __expf(p3) : 0.f;
            den += w2 + w3;
            f16x2 wp2 = (f16x2){(_Float16)w2, (_Float16)w2};
            f16x2 wp3 = (f16x2){(_Float16)w3, (_Float16)w3};
            ACC_ROW(wp2, r2)
            ACC_ROW(wp3, r3)
        }
        if (j + 16 < s1) {  // pair 2 (execz-skips whole wave when deg<=16)
            float p4 = edge_logit8(r4, xr0, xr1, xr2, xr3, a0, a1, a2, a3);
            float p5 = edge_logit8(r5, xr0, xr1, xr2, xr3, a0, a1, a2, a3);
            p4 = qp_xor_add<0xB1>(p4); p4 = qp_xor_add<0x4E>(p4);
            p5 = qp_xor_add<0xB1>(p5); p5 = qp_xor_add<0x4E>(p5);
            float w4 = __expf(p4);
            float w5 = (j + 17 < s1) ? __expf(p5) : 0.f;
            den += w4 + w5;
            f16x2 wp4 = (f16x2){(_Float16)w4, (_Float16)w4};
            f16x2 wp5 = (f16x2){(_Float16)w5, (_Float16)w5};
            ACC_ROW(wp4, r4)
            ACC_ROW(wp5, r5)
        }
    } else if (deg > 24) {
        // ---- slow path: depth-2 pipeline, predicated prefetch ----
        const int last = s1 - 1;
        int jj = j;
        // prologue: all 4 rows valid (deg>=25 => jj+9 <= s0+15 < s1)
        f16x8 pa0 = *(const f16x8*)(xlb + csr_off[jj]);
        f16x8 pb0 = *(const f16x8*)(xlb + csr_off[jj + 1]);
        f16x8 pa1 = *(const f16x8*)(xlb + csr_off[jj + 8]);
        f16x8 pb1 = *(const f16x8*)(xlb + csr_off[jj + 9]);
        int oa = csr_off[min(jj + 16, last)];
        int ob = csr_off[min(jj + 17, last)];
        while (jj < s1) {
            f16x8 ca = pa0, cb = pb0;
            pa0 = pa1; pb0 = pb1;
            if (jj + 16 < s1) {          // predicated prefetch: no dup gathers
                pa1 = *(const f16x8*)(xlb + oa);
                pb1 = *(const f16x8*)(xlb + ob);
                oa = csr_off[min(jj + 24, last)];
                ob = csr_off[min(jj + 25, last)];
            } else { pa1 = zero8(); pb1 = zero8(); }

            float pa = edge_logit8(ca, xr0, xr1, xr2, xr3, a0, a1, a2, a3);
            float pb = edge_logit8(cb, xr0, xr1, xr2, xr3, a0, a1, a2, a3);
            pa = qp_xor_add<0xB1>(pa); pa = qp_xor_add<0x4E>(pa);
            pb = qp_xor_add<0xB1>(pb); pb = qp_xor_add<0x4E>(pb);
            float wa = __expf(pa);
            float wb = (jj + 1 < s1) ? __expf(pb) : 0.f;
            den += wa + wb;
            f16x2 wpa = (f16x2){(_Float16)wa, (_Float16)wa};
            f16x2 wpb = (f16x2){(_Float16)wb, (_Float16)wb};
            ACC_ROW(wpa, ca)
            ACC_ROW(wpb, cb)
            jj += 8;
        }
    }

    // merge the four streams (lane stride 16/32) on packed f16x2
    den += __shfl_xor(den, 16);
    den += __shfl_xor(den, 32);
    #pragma unroll
    for (int q = 0; q < 4; q++) {
        float pk = __builtin_bit_cast(float, acc16[q]);
        acc16[q] += __builtin_bit_cast(f16x2, __shfl_xor(pk, 16));
        pk = __builtin_bit_cast(float, acc16[q]);
        acc16[q] += __builtin_bit_cast(f16x2, __shfl_xor(pk, 32));
    }

    if (strm == 0) {
        float acc[8];
        #pragma unroll
        for (int q = 0; q < 4; q++) {
            acc[2 * q]     = (float)acc16[q][0];
            acc[2 * q + 1] = (float)acc16[q][1];
        }
        float4 bA = *(const float4*)(bias + 8 * l16);
        float4 bB = *(const float4*)(bias + 8 * l16 + 4);
        float b[8] = {bA.x, bA.y, bA.z, bA.w, bB.x, bB.y, bB.z, bB.w};
        float inv = (den > 0.f) ? 1.f / den : 0.f;
        float v[8];
        #pragma unroll
        for (int q = 0; q < 8; q++) v[q] = fmaxf(acc[q] * inv + b[q], 0.f);
        if (add_res) {
            f16x8 r = *(const f16x8*)(xres + (size_t)n * HID + 8 * l16);
            #pragma unroll
            for (int q = 0; q < 8; q++) v[q] += (float)r[q];
        }
        if (want_half) {
            f16x8 h;
            #pragma unroll
            for (int q = 0; q < 8; q++) h[q] = (_Float16)v[q];
            *(f16x8*)(outx + (size_t)n * HID + 8 * l16) = h;
        } else {
            *(float4*)(out + (size_t)n * HID + 8 * l16)     = make_float4(v[0], v[1], v[2], v[3]);
            *(float4*)(out + (size_t)n * HID + 8 * l16 + 4) = make_float4(v[4], v[5], v[6], v[7]);
        }
    }
}

// ---------------- Graph readout: mean + max over nodes ----------------

__global__ __launch_bounds__(256) void k_reduce1(const float* __restrict__ x, int N,
                                                 float* __restrict__ psum, float* __restrict__ pmax) {
    __shared__ float ls[8][HID];
    __shared__ float lm[8][HID];
    const int c4 = (threadIdx.x & 31) << 2;   // channel base
    const int rl = threadIdx.x >> 5;          // row lane 0..7
    const int per = (N + gridDim.x - 1) / gridDim.x;
    const int n0 = blockIdx.x * per, n1 = min(N, n0 + per);
    float4 s = make_float4(0.f, 0.f, 0.f, 0.f);
    float4 m = make_float4(-INFINITY, -INFINITY, -INFINITY, -INFINITY);
    for (int n = n0 + rl; n < n1; n += 8) {
        float4 v = *(const float4*)(x + (size_t)n * HID + c4);
        s.x += v.x; s.y += v.y; s.z += v.z; s.w += v.w;
        m.x = fmaxf(m.x, v.x); m.y = fmaxf(m.y, v.y);
        m.z = fmaxf(m.z, v.z); m.w = fmaxf(m.w, v.w);
    }
    *(float4*)&ls[rl][c4] = s;
    *(float4*)&lm[rl][c4] = m;
    __syncthreads();
    if (rl < 4) {
        float4 a = *(float4*)&ls[rl][c4], bq = *(float4*)&ls[rl + 4][c4];
        a.x += bq.x; a.y += bq.y; a.z += bq.z; a.w += bq.w;
        *(float4*)&ls[rl][c4] = a;
        float4 am = *(float4*)&lm[rl][c4], bm = *(float4*)&lm[rl + 4][c4];
        am.x = fmaxf(am.x, bm.x); am.y = fmaxf(am.y, bm.y);
        am.z = fmaxf(am.z, bm.z); am.w = fmaxf(am.w, bm.w);
        *(float4*)&lm[rl][c4] = am;
    }
    __syncthreads();
    if (rl < 2) {
        float4 a = *(float4*)&ls[rl][c4], bq = *(float4*)&ls[rl + 2][c4];
        a.x += bq.x; a.y += bq.y; a.z += bq.z; a.w += bq.w;
        *(float4*)&ls[rl][c4] = a;
        float4 am = *(float4*)&lm[rl][c4], bm = *(float4*)&lm[rl + 2][c4];
        am.x = fmaxf(am.x, bm.x); am.y = fmaxf(am.y, bm.y);
        am.z = fmaxf(am.z, bm.z); am.w = fmaxf(am.w, bm.w);
        *(float4*)&lm[rl][c4] = am;
    }
    __syncthreads();
    if (rl == 0) {
        float4 a = *(float4*)&ls[0][c4], bq = *(float4*)&ls[1][c4];
        a.x += bq.x; a.y += bq.y; a.z += bq.z; a.w += bq.w;
        *(float4*)(psum + (size_t)blockIdx.x * HID + c4) = a;
        float4 am = *(float4*)&lm[0][c4], bm = *(float4*)&lm[1][c4];
        am.x = fmaxf(am.x, bm.x); am.y = fmaxf(am.y, bm.y);
        am.z = fmaxf(am.z, bm.z); am.w = fmaxf(am.w, bm.w);
        *(float4*)(pmax + (size_t)blockIdx.x * HID + c4) = am;
    }
}

__global__ __launch_bounds__(1024) void k_reduce2(const float* __restrict__ psum, const float* __restrict__ pmax,
                                                  int nb, float* __restrict__ out, float invN) {
    __shared__ float ss[8][HID];
    __shared__ float sm[8][HID];
    int h = threadIdx.x & 127;
    int c = threadIdx.x >> 7;          // chunk 0..7
    int per = nb >> 3;
    float s = 0.f, m = -INFINITY;
    for (int b = c * per; b < (c + 1) * per; b++) {
        s += psum[b * HID + h];
        m = fmaxf(m, pmax[b * HID + h]);
    }
    ss[c][h] = s; sm[c][h] = m;
    __syncthreads();
    if (c < 4) { ss[c][h] += ss[c + 4][h]; sm[c][h] = fmaxf(sm[c][h], sm[c + 4][h]); }
    __syncthreads();
    if (c < 2) { ss[c][h] += ss[c + 2][h]; sm[c][h] = fmaxf(sm[c][h], sm[c + 2][h]); }
    __syncthreads();
    if (c == 0) {
        out[h] = (ss[0][h] + ss[1][h]) * invN;
        out[HID + h] = fmaxf(sm[0][h], sm[1][h]);
    }
}

// ---------------- Launch ----------------

extern "C" void kernel_launch(void* const* d_in, const int* in_sizes, int n_in,
                              void* d_out, int out_size, void* d_ws, size_t ws_size,
                              hipStream_t stream) {
    const float* nf    = (const float*)d_in[0];
    const int*   ei    = (const int*)d_in[1];
    const float* W_emb = (const float*)d_in[3];
    const float* b_emb = (const float*)d_in[4];
    const float* Wl    = (const float*)d_in[5];
    const float* bl    = (const float*)d_in[6];
    const float* Wr    = (const float*)d_in[7];
    const float* br    = (const float*)d_in[8];
    const float* att   = (const float*)d_in[9];
    const float* bias  = (const float*)d_in[10];

    const int N = in_sizes[0] / 11;
    const int E = in_sizes[1] / 2;
    const int* src = ei;
    const int* dst = ei + E;

    float* out  = (float*)d_out;
    float* xout = out + 2 * HID;

    // workspace carve-up
    char* w = (char*)d_ws;
    _Float16* xlh  = (_Float16*)w; w += (size_t)N * HID * 2;
    _Float16* xrh  = (_Float16*)w; w += (size_t)N * HID * 2;
    _Float16* xA   = (_Float16*)w; w += (size_t)N * HID * 2;
    _Float16* xB   = (_Float16*)w; w += (size_t)N * HID * 2;
    _Float16* WfL  = (_Float16*)w; w += (size_t)4 * HID * HID * 2;
    _Float16* WfR  = (_Float16*)w; w += (size_t)4 * HID * HID * 2;
    int*   gcnt    = (int*)w;   w += (size_t)256 * 4;
    int*   rowptr  = (int*)w;   w += (size_t)(N + 1) * 4;
    int*   arena   = (int*)w;   w += (size_t)256 * BCAP * 4;
    int*   csr_off = (int*)w;   w += (size_t)E * 4;
    float* psum    = (float*)w; w += (size_t)R1B * HID * 4;
    float* pmax    = (float*)w; w += (size_t)R1B * HID * 4;

    const int nbk = (N + 255) >> 8;       // 196 buckets
    const int nW = 4 * HID * HID;

    // fused: embedding + weight fp16 conversion + gcnt zeroing
    const int nEmb = (N + 1) / 2;
    k_prep<<<nEmb + 128, 256, 0, stream>>>(nf, W_emb, b_emb, xA, N,
                                           Wl, Wr, WfL, WfR, gcnt, nW);

    // CSR build (binned two-phase; binB self-scans bucket prefix)
    k_binA<<<(E + ACHUNK - 1) / ACHUNK, 256, 0, stream>>>(src, dst, E, gcnt, arena);
    k_binB<<<nbk, 256, 0, stream>>>(arena, gcnt, N, E, rowptr, csr_off);

    dim3 lgrid((N + 255) / 256, 2);
    for (int i = 0; i < 4; i++) {
        // ping-pong: even layers read A write B, odd layers read B write A
        const _Float16* xin = (i & 1) ? xB : xA;
        _Float16* xo        = (i & 1) ? xA : xB;
        k_linear_mfma<<<lgrid, 512, 0, stream>>>(xin,
                                                 WfL + (size_t)i * HID * HID, WfR + (size_t)i * HID * HID,
                                                 bl + i * HID, br + i * HID, xlh, xrh, N);
        k_attn<<<(N + 3) / 4, 256, 0, stream>>>(xlh, xrh, rowptr, csr_off,
                                                att + i * HEADS * 32, bias + i * HID,
                                                xin, xo, xout,
                                                i > 0 ? 1 : 0, i < 3 ? 1 : 0, N);
    }

    k_reduce1<<<R1B, 256, 0, stream>>>(xout, N, psum, pmax);
    k_reduce2<<<1, 1024, 0, stream>>>(psum, pmax, R1B, out, 1.0f / N);
}

// Round 9
// 350.435 us; speedup vs baseline: 1.1343x; 1.0108x over previous
//
#include <hip/hip_runtime.h>
#include <math.h>

#define HID 128
#define HEADS 4
#define NEG_SLOPE 0.2f
#define R1B 512    // reduce1 grid
#define BCAP 8192  // per-bucket arena capacity (mean 4096, +64 sigma)
#define PB 6144    // binB LDS staging ints
#define ACHUNK 4096

typedef float f32x4 __attribute__((ext_vector_type(4)));
typedef _Float16 f16x8 __attribute__((ext_vector_type(8)));
typedef _Float16 f16x4 __attribute__((ext_vector_type(4)));
typedef _Float16 f16x2 __attribute__((ext_vector_type(2)));

#if defined(__has_builtin)
#if __has_builtin(__builtin_amdgcn_fdot2)
#define HAVE_FDOT2 1
#endif
#endif

// ---------------- CSR build: two-phase binned counting sort ----------------

// Phase A: bin 4096 edges/block into bucket arenas. Record = (src<<8)|(dst&255).
__global__ __launch_bounds__(256) void k_binA(const int* __restrict__ src, const int* __restrict__ dst,
                                              int E, int* __restrict__ gcnt, int* __restrict__ arena) {
    __shared__ int lh[256];
    __shared__ int lbase[256];
    __shared__ unsigned short lrank[ACHUNK];
    const int tid = threadIdx.x;
    lh[tid] = 0;
    __syncthreads();
    const int e0 = blockIdx.x * ACHUNK;
    #pragma unroll
    for (int i = 0; i < ACHUNK / 256; i++) {
        int e = e0 + i * 256 + tid;
        if (e < E) {
            int b = dst[e] >> 8;
            lrank[i * 256 + tid] = (unsigned short)atomicAdd(&lh[b], 1);
        }
    }
    __syncthreads();
    if (lh[tid] > 0) lbase[tid] = atomicAdd(&gcnt[tid], lh[tid]);
    __syncthreads();
    #pragma unroll
    for (int i = 0; i < ACHUNK / 256; i++) {
        int e = e0 + i * 256 + tid;
        if (e < E) {
            int d = dst[e];
            int b = d >> 8;
            arena[b * BCAP + lbase[b] + lrank[i * 256 + tid]] = (src[e] << 8) | (d & 255);
        }
    }
}

// Phase B: per bucket -- self-computed bucket prefix, node counts + scan ->
// rowptr; staged, coalesced csr_off dump. csr_off value = src*256.
__global__ __launch_bounds__(256) void k_binB(const int* __restrict__ arena, const int* __restrict__ gcnt,
                                              int N, int E,
                                              int* __restrict__ rowptr, int* __restrict__ csr_off) {
    __shared__ int ncnt[256];
    __shared__ int sbuf[256];
    __shared__ int nstart[256];
    __shared__ int exv[256];
    __shared__ int stage[PB];
    __shared__ unsigned short rk[BCAP];
    const int b = blockIdx.x, tid = threadIdx.x;

    // bucket-prefix scan (gcnt[tid]=0 for tid>=nbk, zeroed by k_prep)
    int gv = gcnt[tid];
    sbuf[tid] = gv;
    __syncthreads();
    for (int off = 1; off < 256; off <<= 1) {
        int t = (tid >= off) ? sbuf[tid - off] : 0;
        __syncthreads();
        sbuf[tid] += t;
        __syncthreads();
    }
    exv[tid] = sbuf[tid] - gv;    // exclusive prefix
    if (b == 0 && tid == 0) rowptr[N] = E;
    __syncthreads();
    const int seg = exv[b];
    const int cnt = gcnt[b];

    ncnt[tid] = 0;
    __syncthreads();
    for (int k = tid; k < cnt; k += 256) {
        int v = arena[b * BCAP + k];
        rk[k] = (unsigned short)atomicAdd(&ncnt[v & 255], 1);
    }
    __syncthreads();
    int c = ncnt[tid];
    sbuf[tid] = c;
    __syncthreads();
    for (int off = 1; off < 256; off <<= 1) {
        int t = (tid >= off) ? sbuf[tid - off] : 0;
        __syncthreads();
        sbuf[tid] += t;
        __syncthreads();
    }
    int myStart = sbuf[tid] - c;   // exclusive
    nstart[tid] = myStart;
    int n = b * 256 + tid;
    if (n < N) rowptr[n] = seg + myStart;
    __syncthreads();
    for (int k = tid; k < cnt; k += 256) {
        int v = arena[b * BCAP + k];
        int pos = nstart[v & 255] + rk[k];
        int val = v & 0xFFFFFF00;
        if (pos < PB) stage[pos] = val;
        else          csr_off[seg + pos] = val;   // statistical overflow guard
    }
    __syncthreads();
    int lim = min(cnt, PB);
    for (int k = tid; k < lim; k += 256) csr_off[seg + k] = stage[k];
}

// ---------------- helpers ----------------

__device__ inline f16x2 absh2(f16x2 v) {
    unsigned u = __builtin_bit_cast(unsigned, v) & 0x7FFF7FFFu;
    return __builtin_bit_cast(f16x2, u);
}

__device__ inline f16x8 zero8() {
    f16x8 z;
    #pragma unroll
    for (int i = 0; i < 8; i++) z[i] = (_Float16)0.f;
    return z;
}

// quad_perm butterfly add via DPP (head groups are hardware quads).
template <int CTRL>
__device__ inline float qp_xor_add(float x) {
    int y = __builtin_amdgcn_update_dpp(0, __builtin_bit_cast(int, x),
                                        CTRL, 0xF, 0xF, true);
    return x + __builtin_bit_cast(float, y);
}

// per-edge logit: leaky_relu(xl+xr) . att  (packed fp16, fdot2 accumulate)
__device__ inline float edge_logit8(f16x8 c,
                                    f16x2 xr0, f16x2 xr1, f16x2 xr2, f16x2 xr3,
                                    f16x2 a0, f16x2 a1, f16x2 a2, f16x2 a3) {
    const f16x2 k06 = (f16x2){(_Float16)0.6f, (_Float16)0.6f};
    const f16x2 k04 = (f16x2){(_Float16)0.4f, (_Float16)0.4f};
    f16x2 c0 = __builtin_shufflevector(c, c, 0, 1);
    f16x2 c1 = __builtin_shufflevector(c, c, 2, 3);
    f16x2 c2 = __builtin_shufflevector(c, c, 4, 5);
    f16x2 c3 = __builtin_shufflevector(c, c, 6, 7);
    f16x2 u0 = c0 + xr0, u1 = c1 + xr1, u2 = c2 + xr2, u3 = c3 + xr3;
    f16x2 l0 = u0 * k06 + absh2(u0) * k04;   // leaky_relu, packed
    f16x2 l1 = u1 * k06 + absh2(u1) * k04;
    f16x2 l2 = u2 * k06 + absh2(u2) * k04;
    f16x2 l3 = u3 * k06 + absh2(u3) * k04;
#ifdef HAVE_FDOT2
    float p = __builtin_amdgcn_fdot2(l0, a0, 0.f, false);
    p = __builtin_amdgcn_fdot2(l1, a1, p, false);
    p = __builtin_amdgcn_fdot2(l2, a2, p, false);
    p = __builtin_amdgcn_fdot2(l3, a3, p, false);
#else
    float p = (float)l0[0] * (float)a0[0] + (float)l0[1] * (float)a0[1]
            + (float)l1[0] * (float)a1[0] + (float)l1[1] * (float)a1[1]
            + (float)l2[0] * (float)a2[0] + (float)l2[1] * (float)a2[1]
            + (float)l3[0] * (float)a3[0] + (float)l3[1] * (float)a3[1];
#endif
    return p;
}

// accumulate one weighted row into acc16[0..3] with LITERAL shuffle indices
#define ACC_ROW(WP, R)                                                        \
    acc16[0] += (WP) * __builtin_shufflevector((R), (R), 0, 1);               \
    acc16[1] += (WP) * __builtin_shufflevector((R), (R), 2, 3);               \
    acc16[2] += (WP) * __builtin_shufflevector((R), (R), 4, 5);               \
    acc16[3] += (WP) * __builtin_shufflevector((R), (R), 6, 7);

// ---------------- Fused prep: embed (blocks < nEmb) + W fp16 convert ----------------

__global__ __launch_bounds__(256) void k_prep(const float* __restrict__ nf, const float* __restrict__ We,
                                              const float* __restrict__ be, _Float16* __restrict__ xh,
                                              int N,
                                              const float* __restrict__ Wl, const float* __restrict__ Wr,
                                              _Float16* __restrict__ WfL, _Float16* __restrict__ WfR,
                                              int* __restrict__ gcnt, int nW) {
    __shared__ float f[2][11];
    const int nEmb = (N + 1) / 2;
    const int bid = blockIdx.x;
    if (bid < nEmb) {
        const int sub = threadIdx.x >> 7;
        const int h   = threadIdx.x & 127;
        const int n   = bid * 2 + sub;
        if (n < N && h < 11) f[sub][h] = nf[(size_t)n * 11 + h];
        __syncthreads();
        if (n >= N) return;
        float acc = be[h];
        #pragma unroll
        for (int k = 0; k < 11; k++) acc += f[sub][k] * We[h * 11 + k];
        xh[(size_t)n * HID + h] = (_Float16)fmaxf(acc, 0.f);
    } else {
        const int tb = bid - nEmb;              // 0..127
        if (tb == 0) gcnt[threadIdx.x] = 0;
        const int mat = tb >> 6;                // 64 blocks per matrix
        const float* x = mat ? Wr : Wl;
        _Float16*    o = mat ? WfR : WfL;
        int base = ((tb & 63) * 256 + threadIdx.x) * 4;
        if (base >= nW) return;
        float4 v = *(const float4*)(x + base);
        f16x4 h = {(_Float16)v.x, (_Float16)v.y, (_Float16)v.z, (_Float16)v.w};
        *(f16x4*)(o + base) = h;
    }
}

// ---------------- MFMA linear, LDS-resident fp16 W, 2 A-tiles/wave ----------------
// Round-9: block 512->256 threads (4 waves, 128 nodes). Old grid was 392
// blocks on 256 CUs = 1.5 blocks/CU (~40% idle). Now 784 blocks ~ 3.1/CU,
// LDS 32KB (per-round transpose 64x136 fits inside the W buffer).

__global__ __launch_bounds__(256, 4) void k_linear_mfma(
        const _Float16* __restrict__ xh,
        const _Float16* __restrict__ WfL, const _Float16* __restrict__ WfR,
        const float* __restrict__ bl, const float* __restrict__ br,
        _Float16* __restrict__ xlh, _Float16* __restrict__ xrh, int N) {
    __shared__ _Float16 lds[16384];   // W fp16 swizzled; reused for C transpose
    const int t   = threadIdx.x;
    const int mat = blockIdx.y;
    const _Float16* W = mat ? WfR : WfL;

    for (int g = t; g < 2048; g += 256) {
        int r = g >> 4, cc = g & 15;
        int dsto = r * 128 + ((cc ^ (r & 7)) << 3);      // half units
        *(float4*)&lds[dsto] = *(const float4*)(W + g * 8);
    }
    __syncthreads();

    const int wave = t >> 6;
    const int lane = t & 63;
    const int l16  = lane & 15;
    const int quad = lane >> 4;
    const int n0   = blockIdx.x * 128 + wave * 32;

    int arow0 = n0 + l16;
    int arow1 = n0 + 16 + l16;
    if (arow0 >= N) arow0 = N - 1;     // clamp loads; stores guarded below
    if (arow1 >= N) arow1 = N - 1;

    f32x4 acc[2][8];
    #pragma unroll
    for (int u = 0; u < 2; u++)
        #pragma unroll
        for (int s = 0; s < 8; s++) acc[u][s] = (f32x4){0.f, 0.f, 0.f, 0.f};

    #pragma unroll
    for (int k0 = 0; k0 < HID; k0 += 32) {
        f16x8 a0 = *(const f16x8*)(xh + arow0 * HID + k0 + quad * 8);
        f16x8 a1 = *(const f16x8*)(xh + arow1 * HID + k0 + quad * 8);
        const int cc = (k0 >> 3) + quad;
        #pragma unroll
        for (int s = 0; s < 8; s++) {
            const int row = s * 16 + l16;
            const int off = row * 128 + ((cc ^ (l16 & 7)) << 3);
            f16x8 b = *(const f16x8*)&lds[off];
            acc[0][s] = __builtin_amdgcn_mfma_f32_16x16x32_f16(a0, b, acc[0][s], 0, 0, 0);
            acc[1][s] = __builtin_amdgcn_mfma_f32_16x16x32_f16(a1, b, acc[1][s], 0, 0, 0);
        }
    }

    const float* bias = mat ? br : bl;
    _Float16* dst = mat ? xrh : xlh;
    const int wl = wave & 1;            // wave index within a round

    #pragma unroll
    for (int round = 0; round < 2; round++) {
        __syncthreads();                 // W (or previous round) fully consumed
        if ((wave >> 1) == round) {
            #pragma unroll
            for (int s = 0; s < 8; s++) {
                int col = s * 16 + l16;
                float bv = bias[col];
                #pragma unroll
                for (int u = 0; u < 2; u++) {
                    #pragma unroll
                    for (int r = 0; r < 4; r++) {
                        int nd = wl * 32 + u * 16 + quad * 4 + r;   // 0..63
                        lds[nd * 136 + col] = (_Float16)(acc[u][s][r] + bv);
                    }
                }
            }
        }
        __syncthreads();
        // coalesced dump: 64 nodes x 256B = 1024 x 16B units
        const int base_node = blockIdx.x * 128 + round * 64;
        #pragma unroll
        for (int it = 0; it < 4; it++) {
            int idx = it * 256 + t;
            int node = base_node + (idx >> 4);
            if (node < N)
                *(float4*)(dst + (size_t)node * HID + (idx & 15) * 8) =
                    *(float4*)&lds[(idx >> 4) * 136 + (idx & 15) * 8];
        }
    }
}

// ---------------- Fused attention: wave per node, 4 edge streams ----------------
// 6-pair upfront loads (gather MLP); per-pair exec-guarded compute. Slow path
// (deg>=25, ~2%): depth-2 predicated pipeline.

__global__ __launch_bounds__(256, 8) void k_attn(const _Float16* __restrict__ xlh, const _Float16* __restrict__ xrh,
                                              const int* __restrict__ rowptr, const int* __restrict__ csr_off,
                                              const float* __restrict__ att, const float* __restrict__ bias,
                                              const _Float16* __restrict__ xres, _Float16* __restrict__ outx,
                                              float* __restrict__ out,
                                              int add_res, int want_half, int N) {
    const int wave = threadIdx.x >> 6;
    const int lane = threadIdx.x & 63;
    const int strm = lane >> 4;          // edge stream 0..3
    const int l16  = lane & 15;          // channels [8*l16, 8*l16+8); head = l16>>2
    const int n = blockIdx.x * 4 + wave;
    if (n >= N) return;

    const float4 aA = *(const float4*)(att + 8 * l16);
    const float4 aB = *(const float4*)(att + 8 * l16 + 4);
    const f16x2 a0 = (f16x2){(_Float16)aA.x, (_Float16)aA.y};
    const f16x2 a1 = (f16x2){(_Float16)aA.z, (_Float16)aA.w};
    const f16x2 a2 = (f16x2){(_Float16)aB.x, (_Float16)aB.y};
    const f16x2 a3 = (f16x2){(_Float16)aB.z, (_Float16)aB.w};
    const f16x8 xrv = *(const f16x8*)(xrh + (size_t)n * HID + 8 * l16);
    const f16x2 xr0 = __builtin_shufflevector(xrv, xrv, 0, 1);
    const f16x2 xr1 = __builtin_shufflevector(xrv, xrv, 2, 3);
    const f16x2 xr2 = __builtin_shufflevector(xrv, xrv, 4, 5);
    const f16x2 xr3 = __builtin_shufflevector(xrv, xrv, 6, 7);
    const int s0 = rowptr[n], s1 = rowptr[n + 1];
    const int deg = s1 - s0;

    float den = 0.f;
    f16x2 acc16[4];
    #pragma unroll
    for (int q = 0; q < 4; q++) acc16[q] = (f16x2){(_Float16)0.f, (_Float16)0.f};

    const char* xlb = (const char*)xlh + l16 * 16;  // lane's 16B slice within a row
    const int j = s0 + 2 * strm;                    // stream's first edge

    if (deg > 0 && deg <= 24) {
        // ---- fast path: loads upfront, compute per-pair exec-guarded ----
        const int last = s1 - 1;
        f16x8 r0 = zero8(), r1 = zero8(), r2 = zero8(),
              r3 = zero8(), r4 = zero8(), r5 = zero8();
        if (j < s1) {
            int o0 = csr_off[j];
            int o1 = csr_off[min(j + 1, last)];
            r0 = *(const f16x8*)(xlb + o0);
            r1 = *(const f16x8*)(xlb + o1);
        }
        if (j + 8 < s1) {
            int o2 = csr_off[j + 8];
            int o3 = csr_off[min(j + 9, last)];
            r2 = *(const f16x8*)(xlb + o2);
            r3 = *(const f16x8*)(xlb + o3);
        }
        if (j + 16 < s1) {
            int o4 = csr_off[j + 16];
            int o5 = csr_off[min(j + 17, last)];
            r4 = *(const f16x8*)(xlb + o4);
            r5 = *(const f16x8*)(xlb + o5);
        }

        if (j < s1) {       // pair 0 (execz-skips only for tiny tails)
            float p0 = edge_logit8(r0, xr0, xr1, xr2, xr3, a0, a1, a2, a3);
            float p1 = edge_logit8(r1, xr0, xr1, xr2, xr3, a0, a1, a2, a3);
            p0 = qp_xor_add<0xB1>(p0); p0 = qp_xor_add<0x4E>(p0);
            p1 = qp_xor_add<0xB1>(p1); p1 = qp_xor_add<0x4E>(p1);
            float w0 = __expf(p0);
            float w1 = (j + 1 < s1) ? __expf(p1) : 0.f;
            den += w0 + w1;
            f16x2 wp0 = (f16x2){(_Float16)w0, (_Float16)w0};
            f16x2 wp1 = (f16x2){(_Float16)w1, (_Float16)w1};
            ACC_ROW(wp0, r0)
            ACC_ROW(wp1, r1)
        }
        if (j + 8 < s1) {   // pair 1 (execz-skips whole wave when deg<=8)
            float p2 = edge_logit8(r2, xr0, xr1, xr2, xr3, a0, a1, a2, a3);
            float p3 = edge_logit8(r3, xr0, xr1, xr2, xr3, a0, a1, a2, a3);
            p2 = qp_xor_add<0xB1>(p2); p2 = qp_xor_add<0x4E>(p2);
            p3 = qp_xor_add<0xB1>(p3); p3 = qp_xor_add<0x4E>(p3);
            float w2 = __expf(p2);
            float w3 = (j + 9 < s1) ? __expf(p3) : 0.f;
            den += w2 + w3;
            f16x2 wp2 = (f16x2){(_Float16)w2, (_Float16)w2};
            f16x2 wp3 = (f16x2){(_Float16)w3, (_Float16)w3};
            ACC_ROW(wp2, r2)
            ACC_ROW(wp3, r3)
        }
        if (j + 16 < s1) {  // pair 2 (execz-skips whole wave when deg<=16)
            float p4 = edge_logit8(r4, xr0, xr1, xr2, xr3, a0, a1, a2, a3);
            float p5 = edge_logit8(r5, xr0, xr1, xr2, xr3, a0, a1, a2, a3);
            p4 = qp_xor_add<0xB1>(p4); p4 = qp_xor_add<0x4E>(p4);
            p5 = qp_xor_add<0xB1>(p5); p5 = qp_xor_add<0x4E>(p5);
            float w4 = __expf(p4);
            float w5 = (j + 17 < s1) ? __expf(p5) : 0.f;
            den += w4 + w5;
            f16x2 wp4 = (f16x2){(_Float16)w4, (_Float16)w4};
            f16x2 wp5 = (f16x2){(_Float16)w5, (_Float16)w5};
            ACC_ROW(wp4, r4)
            ACC_ROW(wp5, r5)
        }
    } else if (deg > 24) {
        // ---- slow path: depth-2 pipeline, predicated prefetch ----
        const int last = s1 - 1;
        int jj = j;
        // prologue: all 4 rows valid (deg>=25 => jj+9 <= s0+15 < s1)
        f16x8 pa0 = *(const f16x8*)(xlb + csr_off[jj]);
        f16x8 pb0 = *(const f16x8*)(xlb + csr_off[jj + 1]);
        f16x8 pa1 = *(const f16x8*)(xlb + csr_off[jj + 8]);
        f16x8 pb1 = *(const f16x8*)(xlb + csr_off[jj + 9]);
        int oa = csr_off[min(jj + 16, last)];
        int ob = csr_off[min(jj + 17, last)];
        while (jj < s1) {
            f16x8 ca = pa0, cb = pb0;
            pa0 = pa1; pb0 = pb1;
            if (jj + 16 < s1) {          // predicated prefetch: no dup gathers
                pa1 = *(const f16x8*)(xlb + oa);
                pb1 = *(const f16x8*)(xlb + ob);
                oa = csr_off[min(jj + 24, last)];
                ob = csr_off[min(jj + 25, last)];
            } else { pa1 = zero8(); pb1 = zero8(); }

            float pa = edge_logit8(ca, xr0, xr1, xr2, xr3, a0, a1, a2, a3);
            float pb = edge_logit8(cb, xr0, xr1, xr2, xr3, a0, a1, a2, a3);
            pa = qp_xor_add<0xB1>(pa); pa = qp_xor_add<0x4E>(pa);
            pb = qp_xor_add<0xB1>(pb); pb = qp_xor_add<0x4E>(pb);
            float wa = __expf(pa);
            float wb = (jj + 1 < s1) ? __expf(pb) : 0.f;
            den += wa + wb;
            f16x2 wpa = (f16x2){(_Float16)wa, (_Float16)wa};
            f16x2 wpb = (f16x2){(_Float16)wb, (_Float16)wb};
            ACC_ROW(wpa, ca)
            ACC_ROW(wpb, cb)
            jj += 8;
        }
    }

    // merge the four streams (lane stride 16/32) on packed f16x2
    den += __shfl_xor(den, 16);
    den += __shfl_xor(den, 32);
    #pragma unroll
    for (int q = 0; q < 4; q++) {
        float pk = __builtin_bit_cast(float, acc16[q]);
        acc16[q] += __builtin_bit_cast(f16x2, __shfl_xor(pk, 16));
        pk = __builtin_bit_cast(float, acc16[q]);
        acc16[q] += __builtin_bit_cast(f16x2, __shfl_xor(pk, 32));
    }

    if (strm == 0) {
        float acc[8];
        #pragma unroll
        for (int q = 0; q < 4; q++) {
            acc[2 * q]     = (float)acc16[q][0];
            acc[2 * q + 1] = (float)acc16[q][1];
        }
        float4 bA = *(const float4*)(bias + 8 * l16);
        float4 bB = *(const float4*)(bias + 8 * l16 + 4);
        float b[8] = {bA.x, bA.y, bA.z, bA.w, bB.x, bB.y, bB.z, bB.w};
        float inv = (den > 0.f) ? 1.f / den : 0.f;
        float v[8];
        #pragma unroll
        for (int q = 0; q < 8; q++) v[q] = fmaxf(acc[q] * inv + b[q], 0.f);
        if (add_res) {
            f16x8 r = *(const f16x8*)(xres + (size_t)n * HID + 8 * l16);
            #pragma unroll
            for (int q = 0; q < 8; q++) v[q] += (float)r[q];
        }
        if (want_half) {
            f16x8 h;
            #pragma unroll
            for (int q = 0; q < 8; q++) h[q] = (_Float16)v[q];
            *(f16x8*)(outx + (size_t)n * HID + 8 * l16) = h;
        } else {
            *(float4*)(out + (size_t)n * HID + 8 * l16)     = make_float4(v[0], v[1], v[2], v[3]);
            *(float4*)(out + (size_t)n * HID + 8 * l16 + 4) = make_float4(v[4], v[5], v[6], v[7]);
        }
    }
}

// ---------------- Graph readout: mean + max over nodes ----------------

__global__ __launch_bounds__(256) void k_reduce1(const float* __restrict__ x, int N,
                                                 float* __restrict__ psum, float* __restrict__ pmax) {
    __shared__ float ls[8][HID];
    __shared__ float lm[8][HID];
    const int c4 = (threadIdx.x & 31) << 2;   // channel base
    const int rl = threadIdx.x >> 5;          // row lane 0..7
    const int per = (N + gridDim.x - 1) / gridDim.x;
    const int n0 = blockIdx.x * per, n1 = min(N, n0 + per);
    float4 s = make_float4(0.f, 0.f, 0.f, 0.f);
    float4 m = make_float4(-INFINITY, -INFINITY, -INFINITY, -INFINITY);
    for (int n = n0 + rl; n < n1; n += 8) {
        float4 v = *(const float4*)(x + (size_t)n * HID + c4);
        s.x += v.x; s.y += v.y; s.z += v.z; s.w += v.w;
        m.x = fmaxf(m.x, v.x); m.y = fmaxf(m.y, v.y);
        m.z = fmaxf(m.z, v.z); m.w = fmaxf(m.w, v.w);
    }
    *(float4*)&ls[rl][c4] = s;
    *(float4*)&lm[rl][c4] = m;
    __syncthreads();
    if (rl < 4) {
        float4 a = *(float4*)&ls[rl][c4], bq = *(float4*)&ls[rl + 4][c4];
        a.x += bq.x; a.y += bq.y; a.z += bq.z; a.w += bq.w;
        *(float4*)&ls[rl][c4] = a;
        float4 am = *(float4*)&lm[rl][c4], bm = *(float4*)&lm[rl + 4][c4];
        am.x = fmaxf(am.x, bm.x); am.y = fmaxf(am.y, bm.y);
        am.z = fmaxf(am.z, bm.z); am.w = fmaxf(am.w, bm.w);
        *(float4*)&lm[rl][c4] = am;
    }
    __syncthreads();
    if (rl < 2) {
        float4 a = *(float4*)&ls[rl][c4], bq = *(float4*)&ls[rl + 2][c4];
        a.x += bq.x; a.y += bq.y; a.z += bq.z; a.w += bq.w;
        *(float4*)&ls[rl][c4] = a;
        float4 am = *(float4*)&lm[rl][c4], bm = *(float4*)&lm[rl + 2][c4];
        am.x = fmaxf(am.x, bm.x); am.y = fmaxf(am.y, bm.y);
        am.z = fmaxf(am.z, bm.z); am.w = fmaxf(am.w, bm.w);
        *(float4*)&lm[rl][c4] = am;
    }
    __syncthreads();
    if (rl == 0) {
        float4 a = *(float4*)&ls[0][c4], bq = *(float4*)&ls[1][c4];
        a.x += bq.x; a.y += bq.y; a.z += bq.z; a.w += bq.w;
        *(float4*)(psum + (size_t)blockIdx.x * HID + c4) = a;
        float4 am = *(float4*)&lm[0][c4], bm = *(float4*)&lm[1][c4];
        am.x = fmaxf(am.x, bm.x); am.y = fmaxf(am.y, bm.y);
        am.z = fmaxf(am.z, bm.z); am.w = fmaxf(am.w, bm.w);
        *(float4*)(pmax + (size_t)blockIdx.x * HID + c4) = am;
    }
}

__global__ __launch_bounds__(1024) void k_reduce2(const float* __restrict__ psum, const float* __restrict__ pmax,
                                                  int nb, float* __restrict__ out, float invN) {
    __shared__ float ss[8][HID];
    __shared__ float sm[8][HID];
    int h = threadIdx.x & 127;
    int c = threadIdx.x >> 7;          // chunk 0..7
    int per = nb >> 3;
    float s = 0.f, m = -INFINITY;
    for (int b = c * per; b < (c + 1) * per; b++) {
        s += psum[b * HID + h];
        m = fmaxf(m, pmax[b * HID + h]);
    }
    ss[c][h] = s; sm[c][h] = m;
    __syncthreads();
    if (c < 4) { ss[c][h] += ss[c + 4][h]; sm[c][h] = fmaxf(sm[c][h], sm[c + 4][h]); }
    __syncthreads();
    if (c < 2) { ss[c][h] += ss[c + 2][h]; sm[c][h] = fmaxf(sm[c][h], sm[c + 2][h]); }
    __syncthreads();
    if (c == 0) {
        out[h] = (ss[0][h] + ss[1][h]) * invN;
        out[HID + h] = fmaxf(sm[0][h], sm[1][h]);
    }
}

// ---------------- Launch ----------------

extern "C" void kernel_launch(void* const* d_in, const int* in_sizes, int n_in,
                              void* d_out, int out_size, void* d_ws, size_t ws_size,
                              hipStream_t stream) {
    const float* nf    = (const float*)d_in[0];
    const int*   ei    = (const int*)d_in[1];
    const float* W_emb = (const float*)d_in[3];
    const float* b_emb = (const float*)d_in[4];
    const float* Wl    = (const float*)d_in[5];
    const float* bl    = (const float*)d_in[6];
    const float* Wr    = (const float*)d_in[7];
    const float* br    = (const float*)d_in[8];
    const float* att   = (const float*)d_in[9];
    const float* bias  = (const float*)d_in[10];

    const int N = in_sizes[0] / 11;
    const int E = in_sizes[1] / 2;
    const int* src = ei;
    const int* dst = ei + E;

    float* out  = (float*)d_out;
    float* xout = out + 2 * HID;

    // workspace carve-up
    char* w = (char*)d_ws;
    _Float16* xlh  = (_Float16*)w; w += (size_t)N * HID * 2;
    _Float16* xrh  = (_Float16*)w; w += (size_t)N * HID * 2;
    _Float16* xA   = (_Float16*)w; w += (size_t)N * HID * 2;
    _Float16* xB   = (_Float16*)w; w += (size_t)N * HID * 2;
    _Float16* WfL  = (_Float16*)w; w += (size_t)4 * HID * HID * 2;
    _Float16* WfR  = (_Float16*)w; w += (size_t)4 * HID * HID * 2;
    int*   gcnt    = (int*)w;   w += (size_t)256 * 4;
    int*   rowptr  = (int*)w;   w += (size_t)(N + 1) * 4;
    int*   arena   = (int*)w;   w += (size_t)256 * BCAP * 4;
    int*   csr_off = (int*)w;   w += (size_t)E * 4;
    float* psum    = (float*)w; w += (size_t)R1B * HID * 4;
    float* pmax    = (float*)w; w += (size_t)R1B * HID * 4;

    const int nbk = (N + 255) >> 8;       // 196 buckets
    const int nW = 4 * HID * HID;

    // fused: embedding + weight fp16 conversion + gcnt zeroing
    const int nEmb = (N + 1) / 2;
    k_prep<<<nEmb + 128, 256, 0, stream>>>(nf, W_emb, b_emb, xA, N,
                                           Wl, Wr, WfL, WfR, gcnt, nW);

    // CSR build (binned two-phase; binB self-scans bucket prefix)
    k_binA<<<(E + ACHUNK - 1) / ACHUNK, 256, 0, stream>>>(src, dst, E, gcnt, arena);
    k_binB<<<nbk, 256, 0, stream>>>(arena, gcnt, N, E, rowptr, csr_off);

    dim3 lgrid((N + 127) / 128, 2);
    for (int i = 0; i < 4; i++) {
        // ping-pong: even layers read A write B, odd layers read B write A
        const _Float16* xin = (i & 1) ? xB : xA;
        _Float16* xo        = (i & 1) ? xA : xB;
        k_linear_mfma<<<lgrid, 256, 0, stream>>>(xin,
                                                 WfL + (size_t)i * HID * HID, WfR + (size_t)i * HID * HID,
                                                 bl + i * HID, br + i * HID, xlh, xrh, N);
        k_attn<<<(N + 3) / 4, 256, 0, stream>>>(xlh, xrh, rowptr, csr_off,
                                                att + i * HEADS * 32, bias + i * HID,
                                                xin, xo, xout,
                                                i > 0 ? 1 : 0, i < 3 ? 1 : 0, N);
    }

    k_reduce1<<<R1B, 256, 0, stream>>>(xout, N, psum, pmax);
    k_reduce2<<<1, 1024, 0, stream>>>(psum, pmax, R1B, out, 1.0f / N);
}